// Round 12
// baseline (1766.593 us; speedup 1.0000x reference)
//
// NeRTModel_60997125538302 — round 12: k4 reverted to r10 (best, 475us; r11's 11-pair
// design spilled at the 128 cap and regressed). New targets = the unprofiled tail:
// k1 score phase was ~51K LDS-b64 issues/block -> replaced with 40 MFMAs/block
//   (16x16x32 per (news,head), K=20 zero-padded to 32) + shfl softmax; tok LDS dropped
//   (pooling re-reads x2 from L2/L3) -> LDS 64KB, 2 blk/CU.
// k5 -> exact cumsum with per-batch constant max (computed in k4b on idle CUs);
//   grid 256 (b x 8 col-chunks), in-place LDS scan. ~10us.

#include <hip/hip_runtime.h>
#include <hip/hip_bf16.h>
#include <cstdint>
#include <cstddef>

typedef unsigned short u16;
typedef __attribute__((ext_vector_type(8))) short short8v;
typedef __attribute__((ext_vector_type(4))) short short4v;
typedef __attribute__((ext_vector_type(4))) float f32x4;
typedef __attribute__((ext_vector_type(4))) int i32x4;

#define MFMA16 __builtin_amdgcn_mfma_f32_16x16x32_bf16
#define MFMAI8 __builtin_amdgcn_mfma_i32_16x16x64_i8

__device__ __forceinline__ float bf2f(u16 u){
  union { unsigned int i; float f; } v; v.i = ((unsigned int)u) << 16; return v.f;
}
__device__ __forceinline__ u16 f2bf(float f){
  union { float f; unsigned int u; } v; v.f = f;
  unsigned int r = v.u + 0x7FFFu + ((v.u >> 16) & 1u);
  return (u16)(r >> 16);
}
__device__ __forceinline__ short8v szero(){
  short8v z;
  #pragma unroll
  for (int i = 0; i < 8; i++) z[i] = 0;
  return z;
}
__device__ __forceinline__ short8v frag_from_f32(const float* p){
  f32x4 a = *(const f32x4*)p;
  f32x4 b = *(const f32x4*)(p + 4);
  short8v s;
  s[0]=f2bf(a[0]); s[1]=f2bf(a[1]); s[2]=f2bf(a[2]); s[3]=f2bf(a[3]);
  s[4]=f2bf(b[0]); s[5]=f2bf(b[1]); s[6]=f2bf(b[2]); s[7]=f2bf(b[3]);
  return s;
}
__device__ __forceinline__ float sigm(float x){ return 1.0f/(1.0f + __expf(-x)); }
__device__ __forceinline__ float tanh_u(float x){
  float e = __expf(2.f*x);              // overflow -> inf -> tanh -> 1 (no NaN)
  return 1.f - 2.f/(e + 1.f);
}
// LDS-visibility-only barrier: does NOT drain vmcnt.
__device__ __forceinline__ void lds_barrier(){
  asm volatile("s_waitcnt lgkmcnt(0)" ::: "memory");
  __builtin_amdgcn_s_barrier();
  __builtin_amdgcn_sched_barrier(0);
}

// ---------------- K0: convert non-recurrent weights f32 -> bf16; fuse LSTM biases ----------------
__global__ void k0_cvt(const float* __restrict__ wq, const float* __restrict__ wk,
                       const float* __restrict__ wihf, const float* __restrict__ wihb,
                       const float* __restrict__ bihf, const float* __restrict__ bhhf,
                       const float* __restrict__ bihb, const float* __restrict__ bhhb,
                       u16* __restrict__ wqb, u16* __restrict__ wkb,
                       u16* __restrict__ wihfb, u16* __restrict__ wihbb,
                       float* __restrict__ bgf, float* __restrict__ bgb){
  int i = blockIdx.x*256 + threadIdx.x;
  if (i < 160000){ wqb[i] = f2bf(wq[i]); wkb[i] = f2bf(wk[i]); }
  if (i < 320000){ wihfb[i] = f2bf(wihf[i]); wihbb[i] = f2bf(wihb[i]); }
  if (i < 800){ bgf[i] = bihf[i] + bhhf[i]; bgb[i] = bihb[i] + bhhb[i]; }
}

// ---------------- K0b: row-quantize W_hh -> i8 [4 gate][208 row][256 k] + scales ----------------
__global__ void k0b_quant(const float* __restrict__ whhf, const float* __restrict__ whhb,
                          signed char* __restrict__ w8f, signed char* __restrict__ w8b,
                          float* __restrict__ sclf, float* __restrict__ sclb){
  const int tid = threadIdx.x, lane = tid & 63, wv = tid >> 6;
  const int widx = blockIdx.x*4 + wv;              // 0..1663
  if (widx < 1600){
    int dir = widx / 800, g = widx - dir*800;
    const float* src = (dir ? whhb : whhf) + (size_t)g*200;
    float mx = 0.f;
    for (int j = lane; j < 200; j += 64) mx = fmaxf(mx, fabsf(src[j]));
    #pragma unroll
    for (int m = 32; m > 0; m >>= 1) mx = fmaxf(mx, __shfl_xor(mx, m, 64));
    float inv = (mx > 0.f) ? 127.f/mx : 0.f;
    int gt = g / 200, hl = g - gt*200;
    signed char* dst = (dir ? w8b : w8f) + (size_t)(gt*208 + hl)*256;
    int e0 = lane*4;
    unsigned int pack = 0u;
    if (e0 < 200){
      #pragma unroll
      for (int r = 0; r < 4; r++){
        int qv = __float2int_rn(src[e0+r]*inv);
        pack |= ((unsigned int)(qv & 255)) << (8*r);
      }
    }
    ((unsigned int*)dst)[lane] = pack;               // lanes 50..63 zero the k-pad
    if (lane == 0) (dir ? sclb : sclf)[g] = mx / 16129.f;   // mx / 127^2
  } else {
    int pr = widx - 1600;                            // 64 pad rows
    int dir = pr >> 5, rem = pr & 31, gt = rem >> 3, hl = 200 + (rem & 7);
    signed char* dst = (dir ? w8b : w8f) + (size_t)(gt*208 + hl)*256;
    ((unsigned int*)dst)[lane] = 0u;
  }
}

// ---------------- K1: per-news word-attention pooling (2 news/block, MFMA scores) ----------------
// qh/kh layout [news][hh][sq][24] bf16 (dims 20..23 zero); scores = 1 MFMA per (news,hh),
// softmax over sk via 16-lane shfl; head-mean via LDS atomicAdd. LDS ~64KB -> 2 blk/CU.
__launch_bounds__(256)
__global__ void k1_pool(const float* __restrict__ x2,
                        const u16* __restrict__ wqb, const float* __restrict__ bq,
                        const u16* __restrict__ wkb, const float* __restrict__ bk,
                        float* __restrict__ pooled){
  __shared__ __align__(16) u16 qh[15360];   // 2 x 20 x 16 x 24
  __shared__ __align__(16) u16 kh[15360];
  __shared__ float msum[2][256];
  __shared__ float tval[2][16];
  __shared__ float attw[2][16];
  const int tid = threadIdx.x;
  const size_t n0 = (size_t)blockIdx.x * 2;
  const float* src = x2 + n0*6400;
  for (int i = tid; i < 7680; i += 256){ ((int*)qh)[i] = 0; ((int*)kh)[i] = 0; }
  for (int i = tid; i < 512; i += 256) ((float*)msum)[i] = 0.f;
  __syncthreads();

  const int lane = tid & 63, wv = tid >> 6;
  const int q = lane & 15, kg = lane >> 4;
  {
    const int proj = wv >> 1;                 // 0: q, 1: k
    const int ntbase = (wv & 1) ? 13 : 0;
    const int ntcnt  = (wv & 1) ? 12 : 13;    // 25 col-tiles total
    const u16* W    = proj ? wkb : wqb;
    const float* bias = proj ? bk : bq;
    u16* dst = proj ? kh : qh;
    short8v A[2][13];
    #pragma unroll
    for (int j = 0; j < 2; j++)
      #pragma unroll
      for (int ksi = 0; ksi < 13; ksi++){
        int e0 = ksi*32 + kg*8;
        A[j][ksi] = (e0 < 400) ? frag_from_f32(&src[(size_t)j*6400 + q*400 + e0]) : szero();
      }
    for (int ti = 0; ti < ntcnt; ti++){
      int col = (ntbase + ti)*16 + q;
      float bv = bias[col];
      f32x4 acc0, acc1;
      acc0[0]=bv; acc0[1]=bv; acc0[2]=bv; acc0[3]=bv; acc1 = acc0;
      const u16* wrow = W + (size_t)col*400;
      #pragma unroll
      for (int ksi = 0; ksi < 13; ksi++){
        int e0 = ksi*32 + kg*8;
        short8v bf = (e0 < 400) ? *(const short8v*)&wrow[e0] : szero();
        acc0 = MFMA16(A[0][ksi], bf, acc0, 0, 0, 0);
        acc1 = MFMA16(A[1][ksi], bf, acc1, 0, 0, 0);
      }
      int hh = col/20, d = col - hh*20;
      #pragma unroll
      for (int r = 0; r < 4; r++){           // D: row sq=(l>>4)*4+r, col=l&15
        int sq = kg*4 + r;
        dst[0*7680 + (hh*16+sq)*24 + d] = f2bf(acc0[r]);
        dst[1*7680 + (hh*16+sq)*24 + d] = f2bf(acc1[r]);
      }
    }
  }
  __syncthreads();
  // score MFMAs: 40 tasks (2 news x 20 hh) / 4 waves = 10 each
  for (int ti = 0; ti < 10; ti++){
    int tsk = wv*10 + ti;
    int nj = tsk / 20, hh = tsk - nj*20;
    short8v qa = (kg < 3) ? *(const short8v*)&qh[nj*7680 + (hh*16+q)*24 + kg*8] : szero();
    short8v ka = (kg < 3) ? *(const short8v*)&kh[nj*7680 + (hh*16+q)*24 + kg*8] : szero();
    f32x4 acc; acc[0]=0.f; acc[1]=0.f; acc[2]=0.f; acc[3]=0.f;
    acc = MFMA16(qa, ka, acc, 0, 0, 0);       // D[sq][sk]: sq=kg*4+r, sk=q
    #pragma unroll
    for (int r = 0; r < 4; r++){
      float s = acc[r] * 0.22360679775f;      // 1/sqrt(20)
      float mx = s;
      #pragma unroll
      for (int m = 1; m < 16; m <<= 1) mx = fmaxf(mx, __shfl_xor(mx, m, 64));
      float e = __expf(s - mx);
      float sum = e;
      #pragma unroll
      for (int m = 1; m < 16; m <<= 1) sum += __shfl_xor(sum, m, 64);
      float p = e/sum * 0.05f;                // fold 1/20 head-mean
      atomicAdd(&msum[nj][(kg*4 + r)*16 + q], p);
    }
  }
  __syncthreads();
  if (tid < 32){                              // mean over sk
    int j = tid >> 4, sq = tid & 15;
    float s = 0.f;
    #pragma unroll
    for (int sk = 0; sk < 16; sk++) s += msum[j][sq*16+sk];
    tval[j][sq] = s * 0.0625f;
  }
  __syncthreads();
  if (tid < 2){                               // softmax over sq
    float mx = -1e30f;
    for (int i = 0; i < 16; i++) mx = fmaxf(mx, tval[tid][i]);
    float sum = 0.f; float ev[16];
    for (int i = 0; i < 16; i++){ ev[i] = __expf(tval[tid][i]-mx); sum += ev[i]; }
    float inv = 1.f/sum;
    for (int i = 0; i < 16; i++) attw[tid][i] = ev[i]*inv;
  }
  __syncthreads();
  for (int e = tid; e < 800; e += 256){       // pooling from global x2 (L2-resident)
    int j = e / 400, c = e - j*400;
    float acc = 0.f;
    #pragma unroll
    for (int s = 0; s < 16; s++) acc += attw[j][s]*src[(size_t)j*6400 + s*400 + c];
    pooled[(n0+j)*400 + c] = acc;
  }
}

// ---------------- K2: x2p = pooled @ w_mlp_mha^T + b (f32 VALU) ----------------
__global__ void k2_x2p(const float* __restrict__ pooled, const float* __restrict__ wmha,
                       const float* __restrict__ bmha, float* __restrict__ x2p){
  __shared__ float rows[3200];
  const int tid = threadIdx.x;
  const size_t n0 = (size_t)blockIdx.x*8;
  for (int i = tid; i < 3200; i += 256) rows[i] = pooled[n0*400 + i];
  __syncthreads();
  for (int j = tid; j < 400; j += 256){
    float bv = bmha[j];
    float acc[8];
    #pragma unroll
    for (int r = 0; r < 8; r++) acc[r] = bv;
    const float* wr = wmha + (size_t)j*400;
    for (int e = 0; e < 400; e += 4){
      const f32x4 w4 = *(const f32x4*)&wr[e];
      #pragma unroll
      for (int r = 0; r < 8; r++){
        const f32x4 x4 = *(const f32x4*)&rows[r*400 + e];
        acc[r] += x4[0]*w4[0] + x4[1]*w4[1] + x4[2]*w4[2] + x4[3]*w4[3];
      }
    }
    #pragma unroll
    for (int r = 0; r < 8; r++) x2p[(n0+r)*400 + j] = acc[r];
  }
}

// ---------------- K3: xW = x @ W_ih^T + (b_ih+b_hh), layout [t][b32][hu][gt] bf16 ----------------
__launch_bounds__(512)
__global__ void k3_xw(const float* __restrict__ x1, const int* __restrict__ seq,
                      const u16* __restrict__ wihfb, const u16* __restrict__ wihbb,
                      const float* __restrict__ bgf, const float* __restrict__ bgb,
                      u16* __restrict__ xWf, u16* __restrict__ xWb){
  __shared__ u16 xf[12800];
  __shared__ u16 xb[12800];
  const int tid = threadIdx.x;
  const int t = blockIdx.x;
  for (int i = tid; i < 3200; i += 512){
    int b = i / 100, e4 = i - b*100;
    f32x4 vf = *(const f32x4*)&x1[((size_t)b*256 + t)*400 + e4*4];
    int rb = seq[b] - 1 - t; if (rb < 0) rb = 0;     // clip(L-1-t, 0, T-1)
    f32x4 vb = *(const f32x4*)&x1[((size_t)b*256 + rb)*400 + e4*4];
    short4v sf, sb;
    #pragma unroll
    for (int r = 0; r < 4; r++){ sf[r] = f2bf(vf[r]); sb[r] = f2bf(vb[r]); }
    ((short4v*)xf)[i] = sf;
    ((short4v*)xb)[i] = sb;
  }
  __syncthreads();
  const int lane = tid & 63, wv = tid >> 6;
  const int dir = wv >> 2, wl = wv & 3;
  const u16* xs = dir ? xb : xf;
  const u16* W  = dir ? wihbb : wihfb;
  const float* bg = dir ? bgb : bgf;
  u16* xW = dir ? xWb : xWf;
  const int q = lane & 15, kg = lane >> 4;
  short8v A[2][13];
  #pragma unroll
  for (int mt = 0; mt < 2; mt++)
    #pragma unroll
    for (int ksi = 0; ksi < 13; ksi++){
      int e0 = ksi*32 + kg*8;
      A[mt][ksi] = (e0 < 400) ? *(const short8v*)&xs[(mt*16 + q)*400 + e0] : szero();
    }
  for (int nt = wl; nt < 50; nt += 4){
    int g = nt*16 + q;                       // gate row 0..799
    float bv = bg[g];
    f32x4 acc0, acc1;
    acc0[0]=bv; acc0[1]=bv; acc0[2]=bv; acc0[3]=bv; acc1 = acc0;
    const u16* wrow = W + (size_t)g*400;
    #pragma unroll
    for (int ksi = 0; ksi < 13; ksi++){
      int e0 = ksi*32 + kg*8;
      short8v bf = (e0 < 400) ? *(const short8v*)&wrow[e0] : szero();
      acc0 = MFMA16(A[0][ksi], bf, acc0, 0,0,0);
      acc1 = MFMA16(A[1][ksi], bf, acc1, 0,0,0);
    }
    int gt = g / 200, hu = g - gt*200;
    #pragma unroll
    for (int r = 0; r < 4; r++){
      int bl = kg*4 + r;                     // D rows = batch rows
      xW[(((size_t)t*32 +      bl)*200 + hu)*4 + gt] = f2bf(acc0[r]);
      xW[(((size_t)t*32 + 16 + bl)*200 + hu)*4 + gt] = f2bf(acc1[r]);
    }
  }
}

// ---------------- K4: sequential BiLSTM (round-10 version). grid 16, 512 thr. ----------------
__device__ __forceinline__ void store_gate_f32(int p, const i32x4& acc, int q, int kg,
                                               float* gates, const float* scl_s){
  int gt = p/13, nt = p - gt*13;
  int hu0 = nt*16 + kg*4;
  if (hu0 < 200 && q < 4){
    const f32x4 s4 = *(const f32x4*)&scl_s[gt*200 + hu0];
    #pragma unroll
    for (int r = 0; r < 4; r++)
      gates[q*804 + (hu0+r)*4 + gt] = (float)acc[r]*s4[r];
  }
}

__launch_bounds__(512)
__global__ void k4_lstm(const u16* __restrict__ xWf, const u16* __restrict__ xWb,
                        const signed char* __restrict__ w8f, const signed char* __restrict__ w8b,
                        const float* __restrict__ sclf, const float* __restrict__ sclb,
                        const int* __restrict__ seq, float* __restrict__ h_ws){
  __shared__ __align__(16) signed char h8[16*288];
  __shared__ __align__(16) float gates[4*804];
  __shared__ __align__(16) i32x4 pool[20*4*64];
  __shared__ float scl_s[800];
  __shared__ int Ls[4];
  const int tid = threadIdx.x;
  const int dir = blockIdx.x >> 3, grp = blockIdx.x & 7;
  const u16* xWd = dir ? xWb : xWf;
  const signed char* w8 = dir ? w8b : w8f;
  const float* scl = dir ? sclb : sclf;
  if (tid < 4) Ls[tid] = seq[grp*4 + tid];
  for (int i = tid; i < 1152; i += 512) ((int*)h8)[i] = 0;
  for (int i = tid; i < 800; i += 512) scl_s[i] = scl[i];
  const int lane = tid & 63, wv = tid >> 6;
  const int q = lane & 15, kg = lane >> 4;
  for (int idx = tid; idx < 20*4*64; idx += 512){
    int s = idx >> 8, rem = idx & 255;
    int ksi = rem >> 6, l = rem & 63;
    int qq = l & 15, kk = l >> 4;
    int p = 32 + s, gt = p/13, nt = p - gt*13;
    pool[idx] = *(const i32x4*)&w8[(size_t)(gt*208 + nt*16 + qq)*256 + ksi*64 + kk*16];
  }
  i32x4 Wr[4][4];
  #pragma unroll
  for (int j = 0; j < 4; j++){
    int p = wv + 8*j, gt = p/13, nt = p - gt*13;
    #pragma unroll
    for (int ksi = 0; ksi < 4; ksi++)
      Wr[j][ksi] = *(const i32x4*)&w8[(size_t)(gt*208 + nt*16 + q)*256 + ksi*64 + kg*16];
  }
  float cst0 = 0.f, cst1 = 0.f;
  const int c0 = tid,        b0c = c0/200, hu0c = c0 - b0c*200;
  const int qd1 = tid + 512;
  const int b1c = qd1/200,   hu1c = qd1 - b1c*200;
  const int xoff0 = ((grp*4 + b0c)*200 + hu0c)*4;
  const int xoff1 = ((grp*4 + b1c)*200 + hu1c)*4;
  short4v xc0 = *(const short4v*)&xWd[xoff0];
  short4v xc1 = {0,0,0,0};
  if (tid < 288) xc1 = *(const short4v*)&xWd[xoff1];
  __syncthreads();
  #pragma unroll 1
  for (int t = 0; t < 256; t++){
    int tn = (t + 1 < 256) ? t + 1 : 255;
    const u16* xwn = xWd + (size_t)tn*25600;
    short4v xn0 = *(const short4v*)&xwn[xoff0];
    short4v xn1 = {0,0,0,0};
    if (tid < 288) xn1 = *(const short4v*)&xwn[xoff1];
    i32x4 bh[4];
    #pragma unroll
    for (int ksi = 0; ksi < 4; ksi++)
      bh[ksi] = *(const i32x4*)&h8[q*288 + ksi*64 + kg*16];
    #pragma unroll
    for (int j = 0; j < 4; j++){
      i32x4 acc = {0,0,0,0};
      #pragma unroll
      for (int ksi = 0; ksi < 4; ksi++)
        acc = MFMAI8(Wr[j][ksi], bh[ksi], acc, 0,0,0);
      store_gate_f32(wv + 8*j, acc, q, kg, gates, scl_s);
    }
    #pragma unroll
    for (int jp = 0; jp < 2; jp++){
      int s = wv + 8*jp;
      i32x4 acc = {0,0,0,0};
      #pragma unroll
      for (int ksi = 0; ksi < 4; ksi++)
        acc = MFMAI8(pool[(s*4 + ksi)*64 + lane], bh[ksi], acc, 0,0,0);
      store_gate_f32(32 + s, acc, q, kg, gates, scl_s);
    }
    if (wv < 4){
      int s = 16 + wv;
      i32x4 acc = {0,0,0,0};
      #pragma unroll
      for (int ksi = 0; ksi < 4; ksi++)
        acc = MFMAI8(pool[(s*4 + ksi)*64 + lane], bh[ksi], acc, 0,0,0);
      store_gate_f32(32 + s, acc, q, kg, gates, scl_s);
    }
    lds_barrier();
    {
      const f32x4 g4 = *(const f32x4*)&gates[b0c*804 + hu0c*4];
      float gi = g4[0] + bf2f((u16)xc0[0]);
      float gf = g4[1] + bf2f((u16)xc0[1]);
      float gg = g4[2] + bf2f((u16)xc0[2]);
      float go = g4[3] + bf2f((u16)xc0[3]);
      float c = sigm(gf)*cst0 + sigm(gi)*tanh_u(gg);
      cst0 = c;
      float hv = sigm(go)*tanh_u(c);
      h8[b0c*288 + hu0c] = (signed char)__float2int_rn(hv*127.f);
      int gb = grp*4 + b0c;
      if (dir == 0){
        h_ws[((size_t)gb*256 + t)*400 + hu0c] = hv;
      } else {
        int tp = Ls[b0c] - 1 - t;
        if (tp >= 0) h_ws[((size_t)gb*256 + tp)*400 + 200 + hu0c] = hv;
      }
    }
    if (tid < 288){
      const f32x4 g4 = *(const f32x4*)&gates[b1c*804 + hu1c*4];
      float gi = g4[0] + bf2f((u16)xc1[0]);
      float gf = g4[1] + bf2f((u16)xc1[1]);
      float gg = g4[2] + bf2f((u16)xc1[2]);
      float go = g4[3] + bf2f((u16)xc1[3]);
      float c = sigm(gf)*cst1 + sigm(gi)*tanh_u(gg);
      cst1 = c;
      float hv = sigm(go)*tanh_u(c);
      h8[b1c*288 + hu1c] = (signed char)__float2int_rn(hv*127.f);
      int gb = grp*4 + b1c;
      if (dir == 0){
        h_ws[((size_t)gb*256 + t)*400 + hu1c] = hv;
      } else {
        int tp = Ls[b1c] - 1 - t;
        if (tp >= 0) h_ws[((size_t)gb*256 + tp)*400 + 200 + hu1c] = hv;
      }
    }
    lds_barrier();
    xc0 = xn0; xc1 = xn1;
  }
}

// ---------------- K4b: fill bwd rows t>=L AND compute a[b][t] = h[t].W_attn + per-b max ----------------
__global__ void k4b_fill(const int* __restrict__ seq, float* __restrict__ h_ws,
                         const float* __restrict__ wattn,
                         float* __restrict__ a_ws, float* __restrict__ amax_ws){
  __shared__ float a_lds[256];
  const int b = blockIdx.x;
  const int tid = threadIdx.x;
  const int lane = tid & 63, wv = tid >> 6;
  const int L = seq[b];
  const int cnt = (256 - L)*200;
  const float* srcf = h_ws + ((size_t)b*256 + (L-1))*400 + 200;
  for (int i = tid; i < cnt; i += 256){
    int tt = L + i/200, cc = i - (i/200)*200;
    h_ws[((size_t)b*256 + tt)*400 + 200 + cc] = srcf[cc];
  }
  __syncthreads();
  for (int row = wv*64; row < wv*64 + 64; row++){
    float s = 0.f;
    for (int j = lane; j < 400; j += 64)
      s += h_ws[((size_t)b*256 + row)*400 + j] * wattn[j];
    #pragma unroll
    for (int m = 32; m > 0; m >>= 1) s += __shfl_xor(s, m, 64);
    if (lane == 0) a_lds[row] = s;
  }
  __syncthreads();
  a_ws[b*256 + tid] = a_lds[tid];
  if (tid < 64){
    float m = fmaxf(fmaxf(a_lds[tid], a_lds[tid+64]), fmaxf(a_lds[tid+128], a_lds[tid+192]));
    #pragma unroll
    for (int mm = 32; mm > 0; mm >>= 1) m = fmaxf(m, __shfl_xor(m, mm, 64));
    if (tid == 0) amax_ws[b] = m;
  }
}

// ---------------- K5: causal attention as exact cumsum (const per-b max). grid 256. ----------------
__launch_bounds__(256)
__global__ void k5_attn(const float* __restrict__ h_ws, const float* __restrict__ a_ws,
                        const float* __restrict__ amax_ws, float* __restrict__ x1_att){
  __shared__ float tile[256*52];       // [t][col-chunk 50, pad 52], in-place h -> out
  __shared__ float wl[256];
  const int tid = threadIdx.x;
  const int b = blockIdx.x >> 3, ch = blockIdx.x & 7;
  const int c0 = ch*50;
  wl[tid] = __expf(a_ws[b*256 + tid] - amax_ws[b]);
  for (int i = tid; i < 12800; i += 256){
    int r = i / 50, c = i - r*50;
    tile[r*52 + c] = h_ws[((size_t)b*256 + r)*400 + c0 + c];
  }
  __syncthreads();
  if (tid < 50){
    float den = 0.f, num = 0.f;
    #pragma unroll 4
    for (int t = 0; t < 256; t++){
      float w = wl[t];
      den += w;
      num += w * tile[t*52 + tid];
      tile[t*52 + tid] = num/den;
    }
  }
  __syncthreads();
  for (int i = tid; i < 12800; i += 256){
    int r = i / 50, c = i - r*50;
    x1_att[((size_t)b*256 + r)*400 + c0 + c] = tile[r*52 + c];
  }
}

// ---------------- K6: out = [x1_att ; x2p] @ w_mlp^T + b, masked, f32 ----------------
__global__ void k6_out(const float* __restrict__ x1_att, const float* __restrict__ x2p,
                       const float* __restrict__ wmlp, const float* __restrict__ bmlp,
                       const int* __restrict__ seq, float* __restrict__ out){
  __shared__ float rows[8*800];
  const int tid = threadIdx.x;
  const size_t n0 = (size_t)blockIdx.x*8;
  const int b = (int)(n0 >> 8), t0 = (int)(n0 & 255);
  const int L = seq[b];
  for (int i = tid; i < 3200; i += 256){
    int r = i / 400, e = i - r*400;
    rows[r*800 + e]       = x1_att[(n0 + r)*400 + e];
    rows[r*800 + 400 + e] = x2p  [(n0 + r)*400 + e];
  }
  __syncthreads();
  for (int e = tid; e < 400; e += 256){
    float bv = bmlp[e];
    float acc[8];
    #pragma unroll
    for (int r = 0; r < 8; r++) acc[r] = bv;
    const float* wr = wmlp + (size_t)e*800;
    for (int j = 0; j < 800; j += 4){
      const f32x4 w4 = *(const f32x4*)&wr[j];
      #pragma unroll
      for (int r = 0; r < 8; r++){
        const f32x4 x4 = *(const f32x4*)&rows[r*800 + j];
        acc[r] += x4[0]*w4[0] + x4[1]*w4[1] + x4[2]*w4[2] + x4[3]*w4[3];
      }
    }
    #pragma unroll
    for (int r = 0; r < 8; r++){
      float v = (t0 + r < L) ? acc[r] : 0.f;
      out[(n0 + r)*400 + e] = v;
    }
  }
}

extern "C" void kernel_launch(void* const* d_in, const int* in_sizes, int n_in,
                              void* d_out, int out_size, void* d_ws, size_t ws_size,
                              hipStream_t stream){
  const float* x1   = (const float*)d_in[0];
  const float* x2   = (const float*)d_in[1];
  // d_in[2] = cate: unused by the reference
  const int*   seq  = (const int*)d_in[3];
  const float* wihf = (const float*)d_in[4];
  const float* whhf = (const float*)d_in[5];
  const float* bihf = (const float*)d_in[6];
  const float* bhhf = (const float*)d_in[7];
  const float* wihb = (const float*)d_in[8];
  const float* whhb = (const float*)d_in[9];
  const float* bihb = (const float*)d_in[10];
  const float* bhhb = (const float*)d_in[11];
  const float* wq   = (const float*)d_in[12];
  const float* bq   = (const float*)d_in[13];
  const float* wk   = (const float*)d_in[14];
  const float* bk   = (const float*)d_in[15];
  const float* wmha = (const float*)d_in[16];
  const float* bmha = (const float*)d_in[17];
  const float* wattn= (const float*)d_in[18];
  // d_in[19] = b_attn: cancels in softmax
  const float* wmlp = (const float*)d_in[20];
  const float* bmlp = (const float*)d_in[21];
  float* out = (float*)d_out;

  char* ws = (char*)d_ws;
  u16*  wqb    = (u16*)(ws + 0);              // 320,000 B
  u16*  wkb    = (u16*)(ws + 320000);         // 320,000
  u16*  wihfb  = (u16*)(ws + 640000);         // 640,000
  u16*  wihbb  = (u16*)(ws + 1280000);        // 640,000
  signed char* w8f  = (signed char*)(ws + 1920000);  // 212,992
  signed char* w8b  = (signed char*)(ws + 2132992);  // 212,992
  float* sclf  = (float*)(ws + 2345984);      // 3,200
  float* sclb  = (float*)(ws + 2349184);      // 3,200
  float* bgf   = (float*)(ws + 2352384);      // 3,200
  float* bgb   = (float*)(ws + 2355584);      // 3,200 -> end 2,358,784
  float* pooled= (float*)(ws + 2359296);      // 13,107,200
  float* x2p   = (float*)(ws + 15466496);     // 13,107,200
  u16*  xWf    = (u16*)(ws + 28573696);       // 13,107,200
  u16*  xWb    = (u16*)(ws + 41680896);       // 13,107,200
  float* h_ws  = (float*)(ws + 54788096);     // 13,107,200 -> end 67,895,296
  float* a_ws  = (float*)(ws + 67895296);     // 32,768
  float* amax_ws=(float*)(ws + 67928064);     // 128 (end ~67.93MB)
  float* x1_att= (float*)(ws + 28573696);     // overlay: xWf dead after k4

  k0_cvt  <<<dim3(1250), dim3(256), 0, stream>>>(wq, wk, wihf, wihb,
                                                 bihf, bhhf, bihb, bhhb,
                                                 wqb, wkb, wihfb, wihbb, bgf, bgb);
  k0b_quant<<<dim3(416), dim3(256), 0, stream>>>(whhf, whhb, w8f, w8b, sclf, sclb);
  k1_pool <<<dim3(4096), dim3(256), 0, stream>>>(x2, wqb, bq, wkb, bk, pooled);
  k3_xw   <<<dim3(256),  dim3(512), 0, stream>>>(x1, seq, wihfb, wihbb, bgf, bgb, xWf, xWb);
  k2_x2p  <<<dim3(1024), dim3(256), 0, stream>>>(pooled, wmha, bmha, x2p);
  k4_lstm <<<dim3(16),   dim3(512), 0, stream>>>(xWf, xWb, w8f, w8b, sclf, sclb, seq, h_ws);
  k4b_fill<<<dim3(32),   dim3(256), 0, stream>>>(seq, h_ws, wattn, a_ws, amax_ws);
  k5_attn <<<dim3(256),  dim3(256), 0, stream>>>(h_ws, a_ws, amax_ws, x1_att);
  k6_out  <<<dim3(1024), dim3(256), 0, stream>>>(x1_att, x2p, wmlp, bmlp, seq, out);
}

// Round 13
// 1345.746 us; speedup vs baseline: 1.3127x; 1.3127x over previous
//
// NeRTModel_60997125538302 — round 13: revert k1 to the round-9 version (LDS tok staging,
// stride-404 q/k, register softmax + shfl head-mean; 538us measured) — round 12's
// "MFMA scores + no tok LDS" made pooling/global reads uncoalesced (845us, FETCH +14MB).
// Keep from r12: k4 = r10 version (475us), k4b computes a[]/amax, k5 = grid-256 exact
// cumsum. One change for clean A/B.

#include <hip/hip_runtime.h>
#include <hip/hip_bf16.h>
#include <cstdint>
#include <cstddef>

typedef unsigned short u16;
typedef __attribute__((ext_vector_type(8))) short short8v;
typedef __attribute__((ext_vector_type(4))) short short4v;
typedef __attribute__((ext_vector_type(4))) float f32x4;
typedef __attribute__((ext_vector_type(4))) int i32x4;

#define MFMA16 __builtin_amdgcn_mfma_f32_16x16x32_bf16
#define MFMAI8 __builtin_amdgcn_mfma_i32_16x16x64_i8

__device__ __forceinline__ float bf2f(u16 u){
  union { unsigned int i; float f; } v; v.i = ((unsigned int)u) << 16; return v.f;
}
__device__ __forceinline__ u16 f2bf(float f){
  union { float f; unsigned int u; } v; v.f = f;
  unsigned int r = v.u + 0x7FFFu + ((v.u >> 16) & 1u);
  return (u16)(r >> 16);
}
__device__ __forceinline__ short8v szero(){
  short8v z;
  #pragma unroll
  for (int i = 0; i < 8; i++) z[i] = 0;
  return z;
}
__device__ __forceinline__ float sigm(float x){ return 1.0f/(1.0f + __expf(-x)); }
__device__ __forceinline__ float tanh_u(float x){
  float e = __expf(2.f*x);              // overflow -> inf -> tanh -> 1 (no NaN)
  return 1.f - 2.f/(e + 1.f);
}
// LDS-visibility-only barrier: does NOT drain vmcnt.
__device__ __forceinline__ void lds_barrier(){
  asm volatile("s_waitcnt lgkmcnt(0)" ::: "memory");
  __builtin_amdgcn_s_barrier();
  __builtin_amdgcn_sched_barrier(0);
}

// ---------------- K0: convert non-recurrent weights f32 -> bf16; fuse LSTM biases ----------------
__global__ void k0_cvt(const float* __restrict__ wq, const float* __restrict__ wk,
                       const float* __restrict__ wihf, const float* __restrict__ wihb,
                       const float* __restrict__ bihf, const float* __restrict__ bhhf,
                       const float* __restrict__ bihb, const float* __restrict__ bhhb,
                       u16* __restrict__ wqb, u16* __restrict__ wkb,
                       u16* __restrict__ wihfb, u16* __restrict__ wihbb,
                       float* __restrict__ bgf, float* __restrict__ bgb){
  int i = blockIdx.x*256 + threadIdx.x;
  if (i < 160000){ wqb[i] = f2bf(wq[i]); wkb[i] = f2bf(wk[i]); }
  if (i < 320000){ wihfb[i] = f2bf(wihf[i]); wihbb[i] = f2bf(wihb[i]); }
  if (i < 800){ bgf[i] = bihf[i] + bhhf[i]; bgb[i] = bihb[i] + bhhb[i]; }
}

// ---------------- K0b: row-quantize W_hh -> i8 [4 gate][208 row][256 k] + scales ----------------
__global__ void k0b_quant(const float* __restrict__ whhf, const float* __restrict__ whhb,
                          signed char* __restrict__ w8f, signed char* __restrict__ w8b,
                          float* __restrict__ sclf, float* __restrict__ sclb){
  const int tid = threadIdx.x, lane = tid & 63, wv = tid >> 6;
  const int widx = blockIdx.x*4 + wv;              // 0..1663
  if (widx < 1600){
    int dir = widx / 800, g = widx - dir*800;
    const float* src = (dir ? whhb : whhf) + (size_t)g*200;
    float mx = 0.f;
    for (int j = lane; j < 200; j += 64) mx = fmaxf(mx, fabsf(src[j]));
    #pragma unroll
    for (int m = 32; m > 0; m >>= 1) mx = fmaxf(mx, __shfl_xor(mx, m, 64));
    float inv = (mx > 0.f) ? 127.f/mx : 0.f;
    int gt = g / 200, hl = g - gt*200;
    signed char* dst = (dir ? w8b : w8f) + (size_t)(gt*208 + hl)*256;
    int e0 = lane*4;
    unsigned int pack = 0u;
    if (e0 < 200){
      #pragma unroll
      for (int r = 0; r < 4; r++){
        int qv = __float2int_rn(src[e0+r]*inv);
        pack |= ((unsigned int)(qv & 255)) << (8*r);
      }
    }
    ((unsigned int*)dst)[lane] = pack;               // lanes 50..63 zero the k-pad
    if (lane == 0) (dir ? sclb : sclf)[g] = mx / 16129.f;   // mx / 127^2
  } else {
    int pr = widx - 1600;                            // 64 pad rows
    int dir = pr >> 5, rem = pr & 31, gt = rem >> 3, hl = 200 + (rem & 7);
    signed char* dst = (dir ? w8b : w8f) + (size_t)(gt*208 + hl)*256;
    ((unsigned int*)dst)[lane] = 0u;
  }
}

// ---------------- K1: per-news word-attention pooling (round-9 version) ----------------
__launch_bounds__(256)
__global__ void k1_pool(const float* __restrict__ x2,
                        const u16* __restrict__ wqb, const float* __restrict__ bq,
                        const u16* __restrict__ wkb, const float* __restrict__ bk,
                        float* __restrict__ pooled){
  __shared__ u16 tok[2][6400];          // 25,600 B
  __shared__ u16 qs [2][16*404];        // 25,856 B (stride 404)
  __shared__ u16 kss[2][16*404];        // 25,856 B
  __shared__ float msum[2][256];
  __shared__ float tval[2][16];
  __shared__ float attw[2][16];
  const int tid = threadIdx.x;
  const size_t n0 = (size_t)blockIdx.x * 2;
  const float* src = x2 + n0*6400;
  for (int i = tid; i < 512; i += 256) ((float*)msum)[i] = 0.f;
  for (int i = tid; i < 3200; i += 256){
    f32x4 v = *(const f32x4*)&src[(size_t)i*4];
    short4v s; s[0]=f2bf(v[0]); s[1]=f2bf(v[1]); s[2]=f2bf(v[2]); s[3]=f2bf(v[3]);
    int j = i / 1600, r = i - j*1600;
    ((short4v*)tok[j])[r] = s;
  }
  __syncthreads();

  const int lane = tid & 63, wv = tid >> 6;
  const int q = lane & 15, kg = lane >> 4;
  {
    const int proj = wv >> 1;                 // 0: q, 1: k
    const int ntbase = (wv & 1) ? 13 : 0;
    const int ntcnt  = (wv & 1) ? 12 : 13;    // 25 col-tiles total
    const u16* W    = proj ? wkb : wqb;
    const float* bias = proj ? bk : bq;
    short8v A[2][13];
    #pragma unroll
    for (int j = 0; j < 2; j++)
      #pragma unroll
      for (int ksi = 0; ksi < 13; ksi++){
        int e0 = ksi*32 + kg*8;
        A[j][ksi] = (e0 < 400) ? *(const short8v*)&tok[j][q*400 + e0] : szero();
      }
    u16* d0 = proj ? kss[0] : qs[0];
    u16* d1 = proj ? kss[1] : qs[1];
    for (int ti = 0; ti < ntcnt; ti++){
      int col = (ntbase + ti)*16 + q;
      float bv = bias[col];
      f32x4 acc0, acc1;
      acc0[0]=bv; acc0[1]=bv; acc0[2]=bv; acc0[3]=bv; acc1 = acc0;
      const u16* wrow = W + (size_t)col*400;
      #pragma unroll
      for (int ksi = 0; ksi < 13; ksi++){
        int e0 = ksi*32 + kg*8;
        short8v bf = (e0 < 400) ? *(const short8v*)&wrow[e0] : szero();
        acc0 = MFMA16(A[0][ksi], bf, acc0, 0, 0, 0);
        acc1 = MFMA16(A[1][ksi], bf, acc1, 0, 0, 0);
      }
      #pragma unroll
      for (int r = 0; r < 4; r++){          // D: row=(l>>4)*4+r, col=l&15
        d0[(kg*4+r)*404 + col] = f2bf(acc0[r]);
        d1[(kg*4+r)*404 + col] = f2bf(acc1[r]);
      }
    }
  }
  __syncthreads();
  // score rows (j,hh,sq): lanes 0-15 share (j,hh) -> k reads broadcast; q stride 404 spread.
  for (int rr = 0; rr < 3; rr++){
    int row = tid + rr*256;
    if (row < 640){
      int j = row / 320, r2 = row - j*320;
      int hh = r2 >> 4, sq = r2 & 15;
      const u16* qrow = &qs[j][sq*404 + hh*20];
      float qv[20];
      #pragma unroll
      for (int d5 = 0; d5 < 5; d5++){
        short4v v = *(const short4v*)&qrow[d5*4];
        qv[d5*4+0]=bf2f((u16)v[0]); qv[d5*4+1]=bf2f((u16)v[1]);
        qv[d5*4+2]=bf2f((u16)v[2]); qv[d5*4+3]=bf2f((u16)v[3]);
      }
      float sc[16]; float mx = -1e30f;
      const u16* kbase = &kss[j][hh*20];
      #pragma unroll
      for (int sk = 0; sk < 16; sk++){
        const u16* krow = kbase + sk*404;
        float s = 0.f;
        #pragma unroll
        for (int d5 = 0; d5 < 5; d5++){
          short4v v = *(const short4v*)&krow[d5*4];
          s += qv[d5*4+0]*bf2f((u16)v[0]) + qv[d5*4+1]*bf2f((u16)v[1])
             + qv[d5*4+2]*bf2f((u16)v[2]) + qv[d5*4+3]*bf2f((u16)v[3]);
        }
        s *= 0.22360679775f;                 // 1/sqrt(20)
        sc[sk] = s; mx = fmaxf(mx, s);
      }
      float sum = 0.f;
      #pragma unroll
      for (int sk = 0; sk < 16; sk++){ sc[sk] = __expf(sc[sk]-mx); sum += sc[sk]; }
      float inv = 0.05f/sum;                 // fold the 1/20 head-mean in
      #pragma unroll
      for (int sk = 0; sk < 16; sk++){
        float v = sc[sk]*inv;
        v += __shfl_xor(v, 16, 64);          // sum the wave's 4 hh values
        v += __shfl_xor(v, 32, 64);
        if (kg == 0) atomicAdd(&msum[j][sq*16 + sk], v);
      }
    }
  }
  __syncthreads();
  if (tid < 32){                             // mean over sk
    int j = tid >> 4, sq = tid & 15;
    float s = 0.f;
    #pragma unroll
    for (int sk = 0; sk < 16; sk++) s += msum[j][sq*16+sk];
    tval[j][sq] = s * 0.0625f;
  }
  __syncthreads();
  if (tid < 2){                              // softmax over sq (16 values)
    float mx = -1e30f;
    for (int i = 0; i < 16; i++) mx = fmaxf(mx, tval[tid][i]);
    float sum = 0.f; float ev[16];
    for (int i = 0; i < 16; i++){ ev[i] = __expf(tval[tid][i]-mx); sum += ev[i]; }
    float inv = 1.f/sum;
    for (int i = 0; i < 16; i++) attw[tid][i] = ev[i]*inv;
  }
  __syncthreads();
  for (int e = tid; e < 800; e += 256){
    int j = e / 400, c = e - j*400;
    float acc = 0.f;
    #pragma unroll
    for (int s = 0; s < 16; s++) acc += attw[j][s]*bf2f(tok[j][s*400 + c]);
    pooled[(n0+j)*400 + c] = acc;
  }
}

// ---------------- K2: x2p = pooled @ w_mlp_mha^T + b (f32 VALU) ----------------
__global__ void k2_x2p(const float* __restrict__ pooled, const float* __restrict__ wmha,
                       const float* __restrict__ bmha, float* __restrict__ x2p){
  __shared__ float rows[3200];
  const int tid = threadIdx.x;
  const size_t n0 = (size_t)blockIdx.x*8;
  for (int i = tid; i < 3200; i += 256) rows[i] = pooled[n0*400 + i];
  __syncthreads();
  for (int j = tid; j < 400; j += 256){
    float bv = bmha[j];
    float acc[8];
    #pragma unroll
    for (int r = 0; r < 8; r++) acc[r] = bv;
    const float* wr = wmha + (size_t)j*400;
    for (int e = 0; e < 400; e += 4){
      const f32x4 w4 = *(const f32x4*)&wr[e];
      #pragma unroll
      for (int r = 0; r < 8; r++){
        const f32x4 x4 = *(const f32x4*)&rows[r*400 + e];
        acc[r] += x4[0]*w4[0] + x4[1]*w4[1] + x4[2]*w4[2] + x4[3]*w4[3];
      }
    }
    #pragma unroll
    for (int r = 0; r < 8; r++) x2p[(n0+r)*400 + j] = acc[r];
  }
}

// ---------------- K3: xW = x @ W_ih^T + (b_ih+b_hh), layout [t][b32][hu][gt] bf16 ----------------
__launch_bounds__(512)
__global__ void k3_xw(const float* __restrict__ x1, const int* __restrict__ seq,
                      const u16* __restrict__ wihfb, const u16* __restrict__ wihbb,
                      const float* __restrict__ bgf, const float* __restrict__ bgb,
                      u16* __restrict__ xWf, u16* __restrict__ xWb){
  __shared__ u16 xf[12800];
  __shared__ u16 xb[12800];
  const int tid = threadIdx.x;
  const int t = blockIdx.x;
  for (int i = tid; i < 3200; i += 512){
    int b = i / 100, e4 = i - b*100;
    f32x4 vf = *(const f32x4*)&x1[((size_t)b*256 + t)*400 + e4*4];
    int rb = seq[b] - 1 - t; if (rb < 0) rb = 0;     // clip(L-1-t, 0, T-1)
    f32x4 vb = *(const f32x4*)&x1[((size_t)b*256 + rb)*400 + e4*4];
    short4v sf, sb;
    #pragma unroll
    for (int r = 0; r < 4; r++){ sf[r] = f2bf(vf[r]); sb[r] = f2bf(vb[r]); }
    ((short4v*)xf)[i] = sf;
    ((short4v*)xb)[i] = sb;
  }
  __syncthreads();
  const int lane = tid & 63, wv = tid >> 6;
  const int dir = wv >> 2, wl = wv & 3;
  const u16* xs = dir ? xb : xf;
  const u16* W  = dir ? wihbb : wihfb;
  const float* bg = dir ? bgb : bgf;
  u16* xW = dir ? xWb : xWf;
  const int q = lane & 15, kg = lane >> 4;
  short8v A[2][13];
  #pragma unroll
  for (int mt = 0; mt < 2; mt++)
    #pragma unroll
    for (int ksi = 0; ksi < 13; ksi++){
      int e0 = ksi*32 + kg*8;
      A[mt][ksi] = (e0 < 400) ? *(const short8v*)&xs[(mt*16 + q)*400 + e0] : szero();
    }
  for (int nt = wl; nt < 50; nt += 4){
    int g = nt*16 + q;                       // gate row 0..799
    float bv = bg[g];
    f32x4 acc0, acc1;
    acc0[0]=bv; acc0[1]=bv; acc0[2]=bv; acc0[3]=bv; acc1 = acc0;
    const u16* wrow = W + (size_t)g*400;
    #pragma unroll
    for (int ksi = 0; ksi < 13; ksi++){
      int e0 = ksi*32 + kg*8;
      short8v bf = (e0 < 400) ? *(const short8v*)&wrow[e0] : szero();
      acc0 = MFMA16(A[0][ksi], bf, acc0, 0,0,0);
      acc1 = MFMA16(A[1][ksi], bf, acc1, 0,0,0);
    }
    int gt = g / 200, hu = g - gt*200;
    #pragma unroll
    for (int r = 0; r < 4; r++){
      int bl = kg*4 + r;                     // D rows = batch rows
      xW[(((size_t)t*32 +      bl)*200 + hu)*4 + gt] = f2bf(acc0[r]);
      xW[(((size_t)t*32 + 16 + bl)*200 + hu)*4 + gt] = f2bf(acc1[r]);
    }
  }
}

// ---------------- K4: sequential BiLSTM (round-10 version). grid 16, 512 thr. ----------------
__device__ __forceinline__ void store_gate_f32(int p, const i32x4& acc, int q, int kg,
                                               float* gates, const float* scl_s){
  int gt = p/13, nt = p - gt*13;
  int hu0 = nt*16 + kg*4;
  if (hu0 < 200 && q < 4){
    const f32x4 s4 = *(const f32x4*)&scl_s[gt*200 + hu0];
    #pragma unroll
    for (int r = 0; r < 4; r++)
      gates[q*804 + (hu0+r)*4 + gt] = (float)acc[r]*s4[r];
  }
}

__launch_bounds__(512)
__global__ void k4_lstm(const u16* __restrict__ xWf, const u16* __restrict__ xWb,
                        const signed char* __restrict__ w8f, const signed char* __restrict__ w8b,
                        const float* __restrict__ sclf, const float* __restrict__ sclb,
                        const int* __restrict__ seq, float* __restrict__ h_ws){
  __shared__ __align__(16) signed char h8[16*288];
  __shared__ __align__(16) float gates[4*804];
  __shared__ __align__(16) i32x4 pool[20*4*64];
  __shared__ float scl_s[800];
  __shared__ int Ls[4];
  const int tid = threadIdx.x;
  const int dir = blockIdx.x >> 3, grp = blockIdx.x & 7;
  const u16* xWd = dir ? xWb : xWf;
  const signed char* w8 = dir ? w8b : w8f;
  const float* scl = dir ? sclb : sclf;
  if (tid < 4) Ls[tid] = seq[grp*4 + tid];
  for (int i = tid; i < 1152; i += 512) ((int*)h8)[i] = 0;
  for (int i = tid; i < 800; i += 512) scl_s[i] = scl[i];
  const int lane = tid & 63, wv = tid >> 6;
  const int q = lane & 15, kg = lane >> 4;
  for (int idx = tid; idx < 20*4*64; idx += 512){
    int s = idx >> 8, rem = idx & 255;
    int ksi = rem >> 6, l = rem & 63;
    int qq = l & 15, kk = l >> 4;
    int p = 32 + s, gt = p/13, nt = p - gt*13;
    pool[idx] = *(const i32x4*)&w8[(size_t)(gt*208 + nt*16 + qq)*256 + ksi*64 + kk*16];
  }
  i32x4 Wr[4][4];
  #pragma unroll
  for (int j = 0; j < 4; j++){
    int p = wv + 8*j, gt = p/13, nt = p - gt*13;
    #pragma unroll
    for (int ksi = 0; ksi < 4; ksi++)
      Wr[j][ksi] = *(const i32x4*)&w8[(size_t)(gt*208 + nt*16 + q)*256 + ksi*64 + kg*16];
  }
  float cst0 = 0.f, cst1 = 0.f;
  const int c0 = tid,        b0c = c0/200, hu0c = c0 - b0c*200;
  const int qd1 = tid + 512;
  const int b1c = qd1/200,   hu1c = qd1 - b1c*200;
  const int xoff0 = ((grp*4 + b0c)*200 + hu0c)*4;
  const int xoff1 = ((grp*4 + b1c)*200 + hu1c)*4;
  short4v xc0 = *(const short4v*)&xWd[xoff0];
  short4v xc1 = {0,0,0,0};
  if (tid < 288) xc1 = *(const short4v*)&xWd[xoff1];
  __syncthreads();
  #pragma unroll 1
  for (int t = 0; t < 256; t++){
    int tn = (t + 1 < 256) ? t + 1 : 255;
    const u16* xwn = xWd + (size_t)tn*25600;
    short4v xn0 = *(const short4v*)&xwn[xoff0];
    short4v xn1 = {0,0,0,0};
    if (tid < 288) xn1 = *(const short4v*)&xwn[xoff1];
    i32x4 bh[4];
    #pragma unroll
    for (int ksi = 0; ksi < 4; ksi++)
      bh[ksi] = *(const i32x4*)&h8[q*288 + ksi*64 + kg*16];
    #pragma unroll
    for (int j = 0; j < 4; j++){
      i32x4 acc = {0,0,0,0};
      #pragma unroll
      for (int ksi = 0; ksi < 4; ksi++)
        acc = MFMAI8(Wr[j][ksi], bh[ksi], acc, 0,0,0);
      store_gate_f32(wv + 8*j, acc, q, kg, gates, scl_s);
    }
    #pragma unroll
    for (int jp = 0; jp < 2; jp++){
      int s = wv + 8*jp;
      i32x4 acc = {0,0,0,0};
      #pragma unroll
      for (int ksi = 0; ksi < 4; ksi++)
        acc = MFMAI8(pool[(s*4 + ksi)*64 + lane], bh[ksi], acc, 0,0,0);
      store_gate_f32(32 + s, acc, q, kg, gates, scl_s);
    }
    if (wv < 4){
      int s = 16 + wv;
      i32x4 acc = {0,0,0,0};
      #pragma unroll
      for (int ksi = 0; ksi < 4; ksi++)
        acc = MFMAI8(pool[(s*4 + ksi)*64 + lane], bh[ksi], acc, 0,0,0);
      store_gate_f32(32 + s, acc, q, kg, gates, scl_s);
    }
    lds_barrier();
    {
      const f32x4 g4 = *(const f32x4*)&gates[b0c*804 + hu0c*4];
      float gi = g4[0] + bf2f((u16)xc0[0]);
      float gf = g4[1] + bf2f((u16)xc0[1]);
      float gg = g4[2] + bf2f((u16)xc0[2]);
      float go = g4[3] + bf2f((u16)xc0[3]);
      float c = sigm(gf)*cst0 + sigm(gi)*tanh_u(gg);
      cst0 = c;
      float hv = sigm(go)*tanh_u(c);
      h8[b0c*288 + hu0c] = (signed char)__float2int_rn(hv*127.f);
      int gb = grp*4 + b0c;
      if (dir == 0){
        h_ws[((size_t)gb*256 + t)*400 + hu0c] = hv;
      } else {
        int tp = Ls[b0c] - 1 - t;
        if (tp >= 0) h_ws[((size_t)gb*256 + tp)*400 + 200 + hu0c] = hv;
      }
    }
    if (tid < 288){
      const f32x4 g4 = *(const f32x4*)&gates[b1c*804 + hu1c*4];
      float gi = g4[0] + bf2f((u16)xc1[0]);
      float gf = g4[1] + bf2f((u16)xc1[1]);
      float gg = g4[2] + bf2f((u16)xc1[2]);
      float go = g4[3] + bf2f((u16)xc1[3]);
      float c = sigm(gf)*cst1 + sigm(gi)*tanh_u(gg);
      cst1 = c;
      float hv = sigm(go)*tanh_u(c);
      h8[b1c*288 + hu1c] = (signed char)__float2int_rn(hv*127.f);
      int gb = grp*4 + b1c;
      if (dir == 0){
        h_ws[((size_t)gb*256 + t)*400 + hu1c] = hv;
      } else {
        int tp = Ls[b1c] - 1 - t;
        if (tp >= 0) h_ws[((size_t)gb*256 + tp)*400 + 200 + hu1c] = hv;
      }
    }
    lds_barrier();
    xc0 = xn0; xc1 = xn1;
  }
}

// ---------------- K4b: fill bwd rows t>=L AND compute a[b][t] + per-b max ----------------
__global__ void k4b_fill(const int* __restrict__ seq, float* __restrict__ h_ws,
                         const float* __restrict__ wattn,
                         float* __restrict__ a_ws, float* __restrict__ amax_ws){
  __shared__ float a_lds[256];
  const int b = blockIdx.x;
  const int tid = threadIdx.x;
  const int lane = tid & 63, wv = tid >> 6;
  const int L = seq[b];
  const int cnt = (256 - L)*200;
  const float* srcf = h_ws + ((size_t)b*256 + (L-1))*400 + 200;
  for (int i = tid; i < cnt; i += 256){
    int tt = L + i/200, cc = i - (i/200)*200;
    h_ws[((size_t)b*256 + tt)*400 + 200 + cc] = srcf[cc];
  }
  __syncthreads();
  for (int row = wv*64; row < wv*64 + 64; row++){
    float s = 0.f;
    for (int j = lane; j < 400; j += 64)
      s += h_ws[((size_t)b*256 + row)*400 + j] * wattn[j];
    #pragma unroll
    for (int m = 32; m > 0; m >>= 1) s += __shfl_xor(s, m, 64);
    if (lane == 0) a_lds[row] = s;
  }
  __syncthreads();
  a_ws[b*256 + tid] = a_lds[tid];
  if (tid < 64){
    float m = fmaxf(fmaxf(a_lds[tid], a_lds[tid+64]), fmaxf(a_lds[tid+128], a_lds[tid+192]));
    #pragma unroll
    for (int mm = 32; mm > 0; mm >>= 1) m = fmaxf(m, __shfl_xor(m, mm, 64));
    if (tid == 0) amax_ws[b] = m;
  }
}

// ---------------- K5: causal attention as exact cumsum (const per-b max). grid 256. ----------------
__launch_bounds__(256)
__global__ void k5_attn(const float* __restrict__ h_ws, const float* __restrict__ a_ws,
                        const float* __restrict__ amax_ws, float* __restrict__ x1_att){
  __shared__ float tile[256*52];       // [t][col-chunk 50, pad 52], in-place h -> out
  __shared__ float wl[256];
  const int tid = threadIdx.x;
  const int b = blockIdx.x >> 3, ch = blockIdx.x & 7;
  const int c0 = ch*50;
  wl[tid] = __expf(a_ws[b*256 + tid] - amax_ws[b]);
  for (int i = tid; i < 12800; i += 256){
    int r = i / 50, c = i - r*50;
    tile[r*52 + c] = h_ws[((size_t)b*256 + r)*400 + c0 + c];
  }
  __syncthreads();
  if (tid < 50){
    float den = 0.f, num = 0.f;
    #pragma unroll 4
    for (int t = 0; t < 256; t++){
      float w = wl[t];
      den += w;
      num += w * tile[t*52 + tid];
      tile[t*52 + tid] = num/den;
    }
  }
  __syncthreads();
  for (int i = tid; i < 12800; i += 256){
    int r = i / 50, c = i - r*50;
    x1_att[((size_t)b*256 + r)*400 + c0 + c] = tile[r*52 + c];
  }
}

// ---------------- K6: out = [x1_att ; x2p] @ w_mlp^T + b, masked, f32 ----------------
__global__ void k6_out(const float* __restrict__ x1_att, const float* __restrict__ x2p,
                       const float* __restrict__ wmlp, const float* __restrict__ bmlp,
                       const int* __restrict__ seq, float* __restrict__ out){
  __shared__ float rows[8*800];
  const int tid = threadIdx.x;
  const size_t n0 = (size_t)blockIdx.x*8;
  const int b = (int)(n0 >> 8), t0 = (int)(n0 & 255);
  const int L = seq[b];
  for (int i = tid; i < 3200; i += 256){
    int r = i / 400, e = i - r*400;
    rows[r*800 + e]       = x1_att[(n0 + r)*400 + e];
    rows[r*800 + 400 + e] = x2p  [(n0 + r)*400 + e];
  }
  __syncthreads();
  for (int e = tid; e < 400; e += 256){
    float bv = bmlp[e];
    float acc[8];
    #pragma unroll
    for (int r = 0; r < 8; r++) acc[r] = bv;
    const float* wr = wmlp + (size_t)e*800;
    for (int j = 0; j < 800; j += 4){
      const f32x4 w4 = *(const f32x4*)&wr[j];
      #pragma unroll
      for (int r = 0; r < 8; r++){
        const f32x4 x4 = *(const f32x4*)&rows[r*800 + j];
        acc[r] += x4[0]*w4[0] + x4[1]*w4[1] + x4[2]*w4[2] + x4[3]*w4[3];
      }
    }
    #pragma unroll
    for (int r = 0; r < 8; r++){
      float v = (t0 + r < L) ? acc[r] : 0.f;
      out[(n0 + r)*400 + e] = v;
    }
  }
}

extern "C" void kernel_launch(void* const* d_in, const int* in_sizes, int n_in,
                              void* d_out, int out_size, void* d_ws, size_t ws_size,
                              hipStream_t stream){
  const float* x1   = (const float*)d_in[0];
  const float* x2   = (const float*)d_in[1];
  // d_in[2] = cate: unused by the reference
  const int*   seq  = (const int*)d_in[3];
  const float* wihf = (const float*)d_in[4];
  const float* whhf = (const float*)d_in[5];
  const float* bihf = (const float*)d_in[6];
  const float* bhhf = (const float*)d_in[7];
  const float* wihb = (const float*)d_in[8];
  const float* whhb = (const float*)d_in[9];
  const float* bihb = (const float*)d_in[10];
  const float* bhhb = (const float*)d_in[11];
  const float* wq   = (const float*)d_in[12];
  const float* bq   = (const float*)d_in[13];
  const float* wk   = (const float*)d_in[14];
  const float* bk   = (const float*)d_in[15];
  const float* wmha = (const float*)d_in[16];
  const float* bmha = (const float*)d_in[17];
  const float* wattn= (const float*)d_in[18];
  // d_in[19] = b_attn: cancels in softmax
  const float* wmlp = (const float*)d_in[20];
  const float* bmlp = (const float*)d_in[21];
  float* out = (float*)d_out;

  char* ws = (char*)d_ws;
  u16*  wqb    = (u16*)(ws + 0);              // 320,000 B
  u16*  wkb    = (u16*)(ws + 320000);         // 320,000
  u16*  wihfb  = (u16*)(ws + 640000);         // 640,000
  u16*  wihbb  = (u16*)(ws + 1280000);        // 640,000
  signed char* w8f  = (signed char*)(ws + 1920000);  // 212,992
  signed char* w8b  = (signed char*)(ws + 2132992);  // 212,992
  float* sclf  = (float*)(ws + 2345984);      // 3,200
  float* sclb  = (float*)(ws + 2349184);      // 3,200
  float* bgf   = (float*)(ws + 2352384);      // 3,200
  float* bgb   = (float*)(ws + 2355584);      // 3,200 -> end 2,358,784
  float* pooled= (float*)(ws + 2359296);      // 13,107,200
  float* x2p   = (float*)(ws + 15466496);     // 13,107,200
  u16*  xWf    = (u16*)(ws + 28573696);       // 13,107,200
  u16*  xWb    = (u16*)(ws + 41680896);       // 13,107,200
  float* h_ws  = (float*)(ws + 54788096);     // 13,107,200 -> end 67,895,296
  float* a_ws  = (float*)(ws + 67895296);     // 32,768
  float* amax_ws=(float*)(ws + 67928064);     // 128 (end ~67.93MB)
  float* x1_att= (float*)(ws + 28573696);     // overlay: xWf dead after k4

  k0_cvt  <<<dim3(1250), dim3(256), 0, stream>>>(wq, wk, wihf, wihb,
                                                 bihf, bhhf, bihb, bhhb,
                                                 wqb, wkb, wihfb, wihbb, bgf, bgb);
  k0b_quant<<<dim3(416), dim3(256), 0, stream>>>(whhf, whhb, w8f, w8b, sclf, sclb);
  k1_pool <<<dim3(4096), dim3(256), 0, stream>>>(x2, wqb, bq, wkb, bk, pooled);
  k3_xw   <<<dim3(256),  dim3(512), 0, stream>>>(x1, seq, wihfb, wihbb, bgf, bgb, xWf, xWb);
  k2_x2p  <<<dim3(1024), dim3(256), 0, stream>>>(pooled, wmha, bmha, x2p);
  k4_lstm <<<dim3(16),   dim3(512), 0, stream>>>(xWf, xWb, w8f, w8b, sclf, sclb, seq, h_ws);
  k4b_fill<<<dim3(32),   dim3(256), 0, stream>>>(seq, h_ws, wattn, a_ws, amax_ws);
  k5_attn <<<dim3(256),  dim3(256), 0, stream>>>(h_ws, a_ws, amax_ws, x1_att);
  k6_out  <<<dim3(1024), dim3(256), 0, stream>>>(x1_att, x2p, wmlp, bmlp, seq, out);
}

// Round 14
// 1103.162 us; speedup vs baseline: 1.6014x; 1.2199x over previous
//
// NeRTModel_60997125538302 — round 14: CONCURRENCY. k4 uses 16 CUs for 475us while 240
// idle; k1 (~450-540us, independent of k4) ran serially after. Fuse them: one launch,
// grid 16+4096, 512 thr. Blocks 0-15 = r10 LSTM (unchanged); blocks 16+ = r9 pooling
// with 8-way wave split (proj x news x tile-half; A-frags 52 VGPR, no spill). Shared
// mem = 102.6KB char union. Order: k0,k0b,k3,fused,k2,k4b,k5,k6.
// Expected: total 1346 -> ~1000us (k1 hides under k4).

#include <hip/hip_runtime.h>
#include <hip/hip_bf16.h>
#include <cstdint>
#include <cstddef>

typedef unsigned short u16;
typedef __attribute__((ext_vector_type(8))) short short8v;
typedef __attribute__((ext_vector_type(4))) short short4v;
typedef __attribute__((ext_vector_type(4))) float f32x4;
typedef __attribute__((ext_vector_type(4))) int i32x4;

#define MFMA16 __builtin_amdgcn_mfma_f32_16x16x32_bf16
#define MFMAI8 __builtin_amdgcn_mfma_i32_16x16x64_i8

__device__ __forceinline__ float bf2f(u16 u){
  union { unsigned int i; float f; } v; v.i = ((unsigned int)u) << 16; return v.f;
}
__device__ __forceinline__ u16 f2bf(float f){
  union { float f; unsigned int u; } v; v.f = f;
  unsigned int r = v.u + 0x7FFFu + ((v.u >> 16) & 1u);
  return (u16)(r >> 16);
}
__device__ __forceinline__ short8v szero(){
  short8v z;
  #pragma unroll
  for (int i = 0; i < 8; i++) z[i] = 0;
  return z;
}
__device__ __forceinline__ float sigm(float x){ return 1.0f/(1.0f + __expf(-x)); }
__device__ __forceinline__ float tanh_u(float x){
  float e = __expf(2.f*x);              // overflow -> inf -> tanh -> 1 (no NaN)
  return 1.f - 2.f/(e + 1.f);
}
// LDS-visibility-only barrier: does NOT drain vmcnt.
__device__ __forceinline__ void lds_barrier(){
  asm volatile("s_waitcnt lgkmcnt(0)" ::: "memory");
  __builtin_amdgcn_s_barrier();
  __builtin_amdgcn_sched_barrier(0);
}

// ---------------- K0: convert non-recurrent weights f32 -> bf16; fuse LSTM biases ----------------
__global__ void k0_cvt(const float* __restrict__ wq, const float* __restrict__ wk,
                       const float* __restrict__ wihf, const float* __restrict__ wihb,
                       const float* __restrict__ bihf, const float* __restrict__ bhhf,
                       const float* __restrict__ bihb, const float* __restrict__ bhhb,
                       u16* __restrict__ wqb, u16* __restrict__ wkb,
                       u16* __restrict__ wihfb, u16* __restrict__ wihbb,
                       float* __restrict__ bgf, float* __restrict__ bgb){
  int i = blockIdx.x*256 + threadIdx.x;
  if (i < 160000){ wqb[i] = f2bf(wq[i]); wkb[i] = f2bf(wk[i]); }
  if (i < 320000){ wihfb[i] = f2bf(wihf[i]); wihbb[i] = f2bf(wihb[i]); }
  if (i < 800){ bgf[i] = bihf[i] + bhhf[i]; bgb[i] = bihb[i] + bhhb[i]; }
}

// ---------------- K0b: row-quantize W_hh -> i8 [4 gate][208 row][256 k] + scales ----------------
__global__ void k0b_quant(const float* __restrict__ whhf, const float* __restrict__ whhb,
                          signed char* __restrict__ w8f, signed char* __restrict__ w8b,
                          float* __restrict__ sclf, float* __restrict__ sclb){
  const int tid = threadIdx.x, lane = tid & 63, wv = tid >> 6;
  const int widx = blockIdx.x*4 + wv;              // 0..1663
  if (widx < 1600){
    int dir = widx / 800, g = widx - dir*800;
    const float* src = (dir ? whhb : whhf) + (size_t)g*200;
    float mx = 0.f;
    for (int j = lane; j < 200; j += 64) mx = fmaxf(mx, fabsf(src[j]));
    #pragma unroll
    for (int m = 32; m > 0; m >>= 1) mx = fmaxf(mx, __shfl_xor(mx, m, 64));
    float inv = (mx > 0.f) ? 127.f/mx : 0.f;
    int gt = g / 200, hl = g - gt*200;
    signed char* dst = (dir ? w8b : w8f) + (size_t)(gt*208 + hl)*256;
    int e0 = lane*4;
    unsigned int pack = 0u;
    if (e0 < 200){
      #pragma unroll
      for (int r = 0; r < 4; r++){
        int qv = __float2int_rn(src[e0+r]*inv);
        pack |= ((unsigned int)(qv & 255)) << (8*r);
      }
    }
    ((unsigned int*)dst)[lane] = pack;               // lanes 50..63 zero the k-pad
    if (lane == 0) (dir ? sclb : sclf)[g] = mx / 16129.f;   // mx / 127^2
  } else {
    int pr = widx - 1600;                            // 64 pad rows
    int dir = pr >> 5, rem = pr & 31, gt = rem >> 3, hl = 200 + (rem & 7);
    signed char* dst = (dir ? w8b : w8f) + (size_t)(gt*208 + hl)*256;
    ((unsigned int*)dst)[lane] = 0u;
  }
}

// ---------------- K3: xW = x @ W_ih^T + (b_ih+b_hh), layout [t][b32][hu][gt] bf16 ----------------
__launch_bounds__(512)
__global__ void k3_xw(const float* __restrict__ x1, const int* __restrict__ seq,
                      const u16* __restrict__ wihfb, const u16* __restrict__ wihbb,
                      const float* __restrict__ bgf, const float* __restrict__ bgb,
                      u16* __restrict__ xWf, u16* __restrict__ xWb){
  __shared__ u16 xf[12800];
  __shared__ u16 xb[12800];
  const int tid = threadIdx.x;
  const int t = blockIdx.x;
  for (int i = tid; i < 3200; i += 512){
    int b = i / 100, e4 = i - b*100;
    f32x4 vf = *(const f32x4*)&x1[((size_t)b*256 + t)*400 + e4*4];
    int rb = seq[b] - 1 - t; if (rb < 0) rb = 0;     // clip(L-1-t, 0, T-1)
    f32x4 vb = *(const f32x4*)&x1[((size_t)b*256 + rb)*400 + e4*4];
    short4v sf, sb;
    #pragma unroll
    for (int r = 0; r < 4; r++){ sf[r] = f2bf(vf[r]); sb[r] = f2bf(vb[r]); }
    ((short4v*)xf)[i] = sf;
    ((short4v*)xb)[i] = sb;
  }
  __syncthreads();
  const int lane = tid & 63, wv = tid >> 6;
  const int dir = wv >> 2, wl = wv & 3;
  const u16* xs = dir ? xb : xf;
  const u16* W  = dir ? wihbb : wihfb;
  const float* bg = dir ? bgb : bgf;
  u16* xW = dir ? xWb : xWf;
  const int q = lane & 15, kg = lane >> 4;
  short8v A[2][13];
  #pragma unroll
  for (int mt = 0; mt < 2; mt++)
    #pragma unroll
    for (int ksi = 0; ksi < 13; ksi++){
      int e0 = ksi*32 + kg*8;
      A[mt][ksi] = (e0 < 400) ? *(const short8v*)&xs[(mt*16 + q)*400 + e0] : szero();
    }
  for (int nt = wl; nt < 50; nt += 4){
    int g = nt*16 + q;                       // gate row 0..799
    float bv = bg[g];
    f32x4 acc0, acc1;
    acc0[0]=bv; acc0[1]=bv; acc0[2]=bv; acc0[3]=bv; acc1 = acc0;
    const u16* wrow = W + (size_t)g*400;
    #pragma unroll
    for (int ksi = 0; ksi < 13; ksi++){
      int e0 = ksi*32 + kg*8;
      short8v bf = (e0 < 400) ? *(const short8v*)&wrow[e0] : szero();
      acc0 = MFMA16(A[0][ksi], bf, acc0, 0,0,0);
      acc1 = MFMA16(A[1][ksi], bf, acc1, 0,0,0);
    }
    int gt = g / 200, hu = g - gt*200;
    #pragma unroll
    for (int r = 0; r < 4; r++){
      int bl = kg*4 + r;                     // D rows = batch rows
      xW[(((size_t)t*32 +      bl)*200 + hu)*4 + gt] = f2bf(acc0[r]);
      xW[(((size_t)t*32 + 16 + bl)*200 + hu)*4 + gt] = f2bf(acc1[r]);
    }
  }
}

// ---------------- K41: FUSED LSTM (blocks 0-15) + pooling (blocks 16+). 512 thr. ----------------
__device__ __forceinline__ void store_gate_f32(int p, const i32x4& acc, int q, int kg,
                                               float* gates, const float* scl_s){
  int gt = p/13, nt = p - gt*13;
  int hu0 = nt*16 + kg*4;
  if (hu0 < 200 && q < 4){
    const f32x4 s4 = *(const f32x4*)&scl_s[gt*200 + hu0];
    #pragma unroll
    for (int r = 0; r < 4; r++)
      gates[q*804 + (hu0+r)*4 + gt] = (float)acc[r]*s4[r];
  }
}

__launch_bounds__(512)
__global__ void k41_fused(const u16* __restrict__ xWf, const u16* __restrict__ xWb,
                          const signed char* __restrict__ w8f, const signed char* __restrict__ w8b,
                          const float* __restrict__ sclf, const float* __restrict__ sclb,
                          const int* __restrict__ seq, float* __restrict__ h_ws,
                          const float* __restrict__ x2,
                          const u16* __restrict__ wqb, const float* __restrict__ bq,
                          const u16* __restrict__ wkb, const float* __restrict__ bk,
                          float* __restrict__ pooled){
  __shared__ __align__(16) char smem[102608];
  const int tid = threadIdx.x;
  const int bid = blockIdx.x;
  const int lane = tid & 63, wv = tid >> 6;
  const int q = lane & 15, kg = lane >> 4;

  if (bid < 16){
    // ============ LSTM path (r10 k4, verbatim; shared mem via union) ============
    signed char* h8   = (signed char*)smem;            // 16*288 = 4,608
    float* gates      = (float*)(smem + 4608);         // 4*804*4 = 12,864 -> 17,472
    i32x4* pool       = (i32x4*)(smem + 17472);        // 20*4*64*16 = 81,920 -> 99,392
    float* scl_s      = (float*)(smem + 99392);        // 3,200 -> 102,592
    int* Ls           = (int*)(smem + 102592);         // 16 -> 102,608
    const int dir = bid >> 3, grp = bid & 7;
    const u16* xWd = dir ? xWb : xWf;
    const signed char* w8 = dir ? w8b : w8f;
    const float* scl = dir ? sclb : sclf;
    if (tid < 4) Ls[tid] = seq[grp*4 + tid];
    for (int i = tid; i < 1152; i += 512) ((int*)h8)[i] = 0;
    for (int i = tid; i < 800; i += 512) scl_s[i] = scl[i];
    for (int idx = tid; idx < 20*4*64; idx += 512){
      int s = idx >> 8, rem = idx & 255;
      int ksi = rem >> 6, l = rem & 63;
      int qq = l & 15, kk = l >> 4;
      int p = 32 + s, gt = p/13, nt = p - gt*13;
      pool[idx] = *(const i32x4*)&w8[(size_t)(gt*208 + nt*16 + qq)*256 + ksi*64 + kk*16];
    }
    i32x4 Wr[4][4];
    #pragma unroll
    for (int j = 0; j < 4; j++){
      int p = wv + 8*j, gt = p/13, nt = p - gt*13;
      #pragma unroll
      for (int ksi = 0; ksi < 4; ksi++)
        Wr[j][ksi] = *(const i32x4*)&w8[(size_t)(gt*208 + nt*16 + q)*256 + ksi*64 + kg*16];
    }
    float cst0 = 0.f, cst1 = 0.f;
    const int c0 = tid,        b0c = c0/200, hu0c = c0 - b0c*200;
    const int qd1 = tid + 512;
    const int b1c = qd1/200,   hu1c = qd1 - b1c*200;
    const int xoff0 = ((grp*4 + b0c)*200 + hu0c)*4;
    const int xoff1 = ((grp*4 + b1c)*200 + hu1c)*4;
    short4v xc0 = *(const short4v*)&xWd[xoff0];
    short4v xc1 = {0,0,0,0};
    if (tid < 288) xc1 = *(const short4v*)&xWd[xoff1];
    __syncthreads();
    #pragma unroll 1
    for (int t = 0; t < 256; t++){
      int tn = (t + 1 < 256) ? t + 1 : 255;
      const u16* xwn = xWd + (size_t)tn*25600;
      short4v xn0 = *(const short4v*)&xwn[xoff0];
      short4v xn1 = {0,0,0,0};
      if (tid < 288) xn1 = *(const short4v*)&xwn[xoff1];
      i32x4 bh[4];
      #pragma unroll
      for (int ksi = 0; ksi < 4; ksi++)
        bh[ksi] = *(const i32x4*)&h8[q*288 + ksi*64 + kg*16];
      #pragma unroll
      for (int j = 0; j < 4; j++){
        i32x4 acc = {0,0,0,0};
        #pragma unroll
        for (int ksi = 0; ksi < 4; ksi++)
          acc = MFMAI8(Wr[j][ksi], bh[ksi], acc, 0,0,0);
        store_gate_f32(wv + 8*j, acc, q, kg, gates, scl_s);
      }
      #pragma unroll
      for (int jp = 0; jp < 2; jp++){
        int s = wv + 8*jp;
        i32x4 acc = {0,0,0,0};
        #pragma unroll
        for (int ksi = 0; ksi < 4; ksi++)
          acc = MFMAI8(pool[(s*4 + ksi)*64 + lane], bh[ksi], acc, 0,0,0);
        store_gate_f32(32 + s, acc, q, kg, gates, scl_s);
      }
      if (wv < 4){
        int s = 16 + wv;
        i32x4 acc = {0,0,0,0};
        #pragma unroll
        for (int ksi = 0; ksi < 4; ksi++)
          acc = MFMAI8(pool[(s*4 + ksi)*64 + lane], bh[ksi], acc, 0,0,0);
        store_gate_f32(32 + s, acc, q, kg, gates, scl_s);
      }
      lds_barrier();
      {
        const f32x4 g4 = *(const f32x4*)&gates[b0c*804 + hu0c*4];
        float gi = g4[0] + bf2f((u16)xc0[0]);
        float gf = g4[1] + bf2f((u16)xc0[1]);
        float gg = g4[2] + bf2f((u16)xc0[2]);
        float go = g4[3] + bf2f((u16)xc0[3]);
        float c = sigm(gf)*cst0 + sigm(gi)*tanh_u(gg);
        cst0 = c;
        float hv = sigm(go)*tanh_u(c);
        h8[b0c*288 + hu0c] = (signed char)__float2int_rn(hv*127.f);
        int gb = grp*4 + b0c;
        if (dir == 0){
          h_ws[((size_t)gb*256 + t)*400 + hu0c] = hv;
        } else {
          int tp = Ls[b0c] - 1 - t;
          if (tp >= 0) h_ws[((size_t)gb*256 + tp)*400 + 200 + hu0c] = hv;
        }
      }
      if (tid < 288){
        const f32x4 g4 = *(const f32x4*)&gates[b1c*804 + hu1c*4];
        float gi = g4[0] + bf2f((u16)xc1[0]);
        float gf = g4[1] + bf2f((u16)xc1[1]);
        float gg = g4[2] + bf2f((u16)xc1[2]);
        float go = g4[3] + bf2f((u16)xc1[3]);
        float c = sigm(gf)*cst1 + sigm(gi)*tanh_u(gg);
        cst1 = c;
        float hv = sigm(go)*tanh_u(c);
        h8[b1c*288 + hu1c] = (signed char)__float2int_rn(hv*127.f);
        int gb = grp*4 + b1c;
        if (dir == 0){
          h_ws[((size_t)gb*256 + t)*400 + hu1c] = hv;
        } else {
          int tp = Ls[b1c] - 1 - t;
          if (tp >= 0) h_ws[((size_t)gb*256 + tp)*400 + 200 + hu1c] = hv;
        }
      }
      lds_barrier();
      xc0 = xn0; xc1 = xn1;
    }
  } else {
    // ============ pooling path (r9 k1 math; 8-way wave split; union shared) ============
    u16* tok0  = (u16*)smem;                 // [2][6400] -> 25,600
    u16* qsb   = (u16*)(smem + 25600);       // [2][16*404] -> 25,856 -> 51,456
    u16* ksb   = (u16*)(smem + 51456);       // 25,856 -> 77,312
    float* msum= (float*)(smem + 77312);     // [2][256] -> 2,048 -> 79,360
    float* tval= (float*)(smem + 79360);     // [2][16]
    float* attw= (float*)(smem + 79488);     // [2][16] -> 79,616
    const int kb = bid - 16;
    const size_t n0 = (size_t)kb * 2;
    const float* src = x2 + n0*6400;
    msum[tid & 511] = 0.f;                   // 512 entries, 512 threads
    for (int i = tid; i < 3200; i += 512){
      f32x4 v = *(const f32x4*)&src[(size_t)i*4];
      short4v s; s[0]=f2bf(v[0]); s[1]=f2bf(v[1]); s[2]=f2bf(v[2]); s[3]=f2bf(v[3]);
      int j = i / 1600, r = i - j*1600;
      ((short4v*)(tok0 + j*6400))[r] = s;
    }
    __syncthreads();
    {
      const int proj = wv >> 2;              // waves 0-3: q, 4-7: k
      const int jn   = (wv >> 1) & 1;        // news index
      const int half = wv & 1;
      const int ntbase = half ? 13 : 0;
      const int ntcnt  = half ? 12 : 13;     // 25 col-tiles total
      const u16* W    = proj ? wkb : wqb;
      const float* bias = proj ? bk : bq;
      const u16* tokj = tok0 + jn*6400;
      u16* dst = (proj ? ksb : qsb) + jn*6464;
      short8v A[13];
      #pragma unroll
      for (int ksi = 0; ksi < 13; ksi++){
        int e0 = ksi*32 + kg*8;
        A[ksi] = (e0 < 400) ? *(const short8v*)&tokj[q*400 + e0] : szero();
      }
      for (int ti = 0; ti < ntcnt; ti++){
        int col = (ntbase + ti)*16 + q;
        float bv = bias[col];
        f32x4 acc;
        acc[0]=bv; acc[1]=bv; acc[2]=bv; acc[3]=bv;
        const u16* wrow = W + (size_t)col*400;
        #pragma unroll
        for (int ksi = 0; ksi < 13; ksi++){
          int e0 = ksi*32 + kg*8;
          short8v bf = (e0 < 400) ? *(const short8v*)&wrow[e0] : szero();
          acc = MFMA16(A[ksi], bf, acc, 0, 0, 0);
        }
        #pragma unroll
        for (int r = 0; r < 4; r++)          // D: row=(l>>4)*4+r, col=l&15
          dst[(kg*4+r)*404 + col] = f2bf(acc[r]);
      }
    }
    __syncthreads();
    // score rows (j,hh,sq); 640 rows over 512 threads (2 passes, pass 2: waves 0-1)
    for (int rr = 0; rr < 2; rr++){
      int row = tid + rr*512;
      if (row < 640){
        int j = row / 320, r2 = row - j*320;
        int hh = r2 >> 4, sq = r2 & 15;
        const u16* qrow = qsb + j*6464 + sq*404 + hh*20;
        float qv[20];
        #pragma unroll
        for (int d5 = 0; d5 < 5; d5++){
          short4v v = *(const short4v*)&qrow[d5*4];
          qv[d5*4+0]=bf2f((u16)v[0]); qv[d5*4+1]=bf2f((u16)v[1]);
          qv[d5*4+2]=bf2f((u16)v[2]); qv[d5*4+3]=bf2f((u16)v[3]);
        }
        float sc[16]; float mx = -1e30f;
        const u16* kbase = ksb + j*6464 + hh*20;
        #pragma unroll
        for (int sk = 0; sk < 16; sk++){
          const u16* krow = kbase + sk*404;
          float s = 0.f;
          #pragma unroll
          for (int d5 = 0; d5 < 5; d5++){
            short4v v = *(const short4v*)&krow[d5*4];
            s += qv[d5*4+0]*bf2f((u16)v[0]) + qv[d5*4+1]*bf2f((u16)v[1])
               + qv[d5*4+2]*bf2f((u16)v[2]) + qv[d5*4+3]*bf2f((u16)v[3]);
          }
          s *= 0.22360679775f;               // 1/sqrt(20)
          sc[sk] = s; mx = fmaxf(mx, s);
        }
        float sum = 0.f;
        #pragma unroll
        for (int sk = 0; sk < 16; sk++){ sc[sk] = __expf(sc[sk]-mx); sum += sc[sk]; }
        float inv = 0.05f/sum;               // fold the 1/20 head-mean in
        #pragma unroll
        for (int sk = 0; sk < 16; sk++){
          float v = sc[sk]*inv;
          v += __shfl_xor(v, 16, 64);        // sum the wave's 4 hh values
          v += __shfl_xor(v, 32, 64);
          if (kg == 0) atomicAdd(&msum[j*256 + sq*16 + sk], v);
        }
      }
    }
    __syncthreads();
    if (tid < 32){                           // mean over sk
      int j = tid >> 4, sq = tid & 15;
      float s = 0.f;
      #pragma unroll
      for (int sk = 0; sk < 16; sk++) s += msum[j*256 + sq*16+sk];
      tval[j*16 + sq] = s * 0.0625f;
    }
    __syncthreads();
    if (tid < 2){                            // softmax over sq (16 values)
      float mx = -1e30f;
      for (int i = 0; i < 16; i++) mx = fmaxf(mx, tval[tid*16+i]);
      float sum = 0.f; float ev[16];
      for (int i = 0; i < 16; i++){ ev[i] = __expf(tval[tid*16+i]-mx); sum += ev[i]; }
      float inv = 1.f/sum;
      for (int i = 0; i < 16; i++) attw[tid*16+i] = ev[i]*inv;
    }
    __syncthreads();
    for (int e = tid; e < 800; e += 512){
      int j = e / 400, c = e - j*400;
      float acc = 0.f;
      #pragma unroll
      for (int s = 0; s < 16; s++) acc += attw[j*16+s]*bf2f(tok0[j*6400 + s*400 + c]);
      pooled[(n0+j)*400 + c] = acc;
    }
  }
}

// ---------------- K2: x2p = pooled @ w_mlp_mha^T + b (f32 VALU) ----------------
__global__ void k2_x2p(const float* __restrict__ pooled, const float* __restrict__ wmha,
                       const float* __restrict__ bmha, float* __restrict__ x2p){
  __shared__ float rows[3200];
  const int tid = threadIdx.x;
  const size_t n0 = (size_t)blockIdx.x*8;
  for (int i = tid; i < 3200; i += 256) rows[i] = pooled[n0*400 + i];
  __syncthreads();
  for (int j = tid; j < 400; j += 256){
    float bv = bmha[j];
    float acc[8];
    #pragma unroll
    for (int r = 0; r < 8; r++) acc[r] = bv;
    const float* wr = wmha + (size_t)j*400;
    for (int e = 0; e < 400; e += 4){
      const f32x4 w4 = *(const f32x4*)&wr[e];
      #pragma unroll
      for (int r = 0; r < 8; r++){
        const f32x4 x4 = *(const f32x4*)&rows[r*400 + e];
        acc[r] += x4[0]*w4[0] + x4[1]*w4[1] + x4[2]*w4[2] + x4[3]*w4[3];
      }
    }
    #pragma unroll
    for (int r = 0; r < 8; r++) x2p[(n0+r)*400 + j] = acc[r];
  }
}

// ---------------- K4b: fill bwd rows t>=L AND compute a[b][t] + per-b max ----------------
__global__ void k4b_fill(const int* __restrict__ seq, float* __restrict__ h_ws,
                         const float* __restrict__ wattn,
                         float* __restrict__ a_ws, float* __restrict__ amax_ws){
  __shared__ float a_lds[256];
  const int b = blockIdx.x;
  const int tid = threadIdx.x;
  const int lane = tid & 63, wv = tid >> 6;
  const int L = seq[b];
  const int cnt = (256 - L)*200;
  const float* srcf = h_ws + ((size_t)b*256 + (L-1))*400 + 200;
  for (int i = tid; i < cnt; i += 256){
    int tt = L + i/200, cc = i - (i/200)*200;
    h_ws[((size_t)b*256 + tt)*400 + 200 + cc] = srcf[cc];
  }
  __syncthreads();
  for (int row = wv*64; row < wv*64 + 64; row++){
    float s = 0.f;
    for (int j = lane; j < 400; j += 64)
      s += h_ws[((size_t)b*256 + row)*400 + j] * wattn[j];
    #pragma unroll
    for (int m = 32; m > 0; m >>= 1) s += __shfl_xor(s, m, 64);
    if (lane == 0) a_lds[row] = s;
  }
  __syncthreads();
  a_ws[b*256 + tid] = a_lds[tid];
  if (tid < 64){
    float m = fmaxf(fmaxf(a_lds[tid], a_lds[tid+64]), fmaxf(a_lds[tid+128], a_lds[tid+192]));
    #pragma unroll
    for (int mm = 32; mm > 0; mm >>= 1) m = fmaxf(m, __shfl_xor(m, mm, 64));
    if (tid == 0) amax_ws[b] = m;
  }
}

// ---------------- K5: causal attention as exact cumsum (const per-b max). grid 256. ----------------
__launch_bounds__(256)
__global__ void k5_attn(const float* __restrict__ h_ws, const float* __restrict__ a_ws,
                        const float* __restrict__ amax_ws, float* __restrict__ x1_att){
  __shared__ float tile[256*52];       // [t][col-chunk 50, pad 52], in-place h -> out
  __shared__ float wl[256];
  const int tid = threadIdx.x;
  const int b = blockIdx.x >> 3, ch = blockIdx.x & 7;
  const int c0 = ch*50;
  wl[tid] = __expf(a_ws[b*256 + tid] - amax_ws[b]);
  for (int i = tid; i < 12800; i += 256){
    int r = i / 50, c = i - r*50;
    tile[r*52 + c] = h_ws[((size_t)b*256 + r)*400 + c0 + c];
  }
  __syncthreads();
  if (tid < 50){
    float den = 0.f, num = 0.f;
    #pragma unroll 4
    for (int t = 0; t < 256; t++){
      float w = wl[t];
      den += w;
      num += w * tile[t*52 + tid];
      tile[t*52 + tid] = num/den;
    }
  }
  __syncthreads();
  for (int i = tid; i < 12800; i += 256){
    int r = i / 50, c = i - r*50;
    x1_att[((size_t)b*256 + r)*400 + c0 + c] = tile[r*52 + c];
  }
}

// ---------------- K6: out = [x1_att ; x2p] @ w_mlp^T + b, masked, f32 ----------------
__global__ void k6_out(const float* __restrict__ x1_att, const float* __restrict__ x2p,
                       const float* __restrict__ wmlp, const float* __restrict__ bmlp,
                       const int* __restrict__ seq, float* __restrict__ out){
  __shared__ float rows[8*800];
  const int tid = threadIdx.x;
  const size_t n0 = (size_t)blockIdx.x*8;
  const int b = (int)(n0 >> 8), t0 = (int)(n0 & 255);
  const int L = seq[b];
  for (int i = tid; i < 3200; i += 256){
    int r = i / 400, e = i - r*400;
    rows[r*800 + e]       = x1_att[(n0 + r)*400 + e];
    rows[r*800 + 400 + e] = x2p  [(n0 + r)*400 + e];
  }
  __syncthreads();
  for (int e = tid; e < 400; e += 256){
    float bv = bmlp[e];
    float acc[8];
    #pragma unroll
    for (int r = 0; r < 8; r++) acc[r] = bv;
    const float* wr = wmlp + (size_t)e*800;
    for (int j = 0; j < 800; j += 4){
      const f32x4 w4 = *(const f32x4*)&wr[j];
      #pragma unroll
      for (int r = 0; r < 8; r++){
        const f32x4 x4 = *(const f32x4*)&rows[r*800 + j];
        acc[r] += x4[0]*w4[0] + x4[1]*w4[1] + x4[2]*w4[2] + x4[3]*w4[3];
      }
    }
    #pragma unroll
    for (int r = 0; r < 8; r++){
      float v = (t0 + r < L) ? acc[r] : 0.f;
      out[(n0 + r)*400 + e] = v;
    }
  }
}

extern "C" void kernel_launch(void* const* d_in, const int* in_sizes, int n_in,
                              void* d_out, int out_size, void* d_ws, size_t ws_size,
                              hipStream_t stream){
  const float* x1   = (const float*)d_in[0];
  const float* x2   = (const float*)d_in[1];
  // d_in[2] = cate: unused by the reference
  const int*   seq  = (const int*)d_in[3];
  const float* wihf = (const float*)d_in[4];
  const float* whhf = (const float*)d_in[5];
  const float* bihf = (const float*)d_in[6];
  const float* bhhf = (const float*)d_in[7];
  const float* wihb = (const float*)d_in[8];
  const float* whhb = (const float*)d_in[9];
  const float* bihb = (const float*)d_in[10];
  const float* bhhb = (const float*)d_in[11];
  const float* wq   = (const float*)d_in[12];
  const float* bq   = (const float*)d_in[13];
  const float* wk   = (const float*)d_in[14];
  const float* bk   = (const float*)d_in[15];
  const float* wmha = (const float*)d_in[16];
  const float* bmha = (const float*)d_in[17];
  const float* wattn= (const float*)d_in[18];
  // d_in[19] = b_attn: cancels in softmax
  const float* wmlp = (const float*)d_in[20];
  const float* bmlp = (const float*)d_in[21];
  float* out = (float*)d_out;

  char* ws = (char*)d_ws;
  u16*  wqb    = (u16*)(ws + 0);              // 320,000 B
  u16*  wkb    = (u16*)(ws + 320000);         // 320,000
  u16*  wihfb  = (u16*)(ws + 640000);         // 640,000
  u16*  wihbb  = (u16*)(ws + 1280000);        // 640,000
  signed char* w8f  = (signed char*)(ws + 1920000);  // 212,992
  signed char* w8b  = (signed char*)(ws + 2132992);  // 212,992
  float* sclf  = (float*)(ws + 2345984);      // 3,200
  float* sclb  = (float*)(ws + 2349184);      // 3,200
  float* bgf   = (float*)(ws + 2352384);      // 3,200
  float* bgb   = (float*)(ws + 2355584);      // 3,200 -> end 2,358,784
  float* pooled= (float*)(ws + 2359296);      // 13,107,200
  float* x2p   = (float*)(ws + 15466496);     // 13,107,200
  u16*  xWf    = (u16*)(ws + 28573696);       // 13,107,200
  u16*  xWb    = (u16*)(ws + 41680896);       // 13,107,200
  float* h_ws  = (float*)(ws + 54788096);     // 13,107,200 -> end 67,895,296
  float* a_ws  = (float*)(ws + 67895296);     // 32,768
  float* amax_ws=(float*)(ws + 67928064);     // 128 (end ~67.93MB)
  float* x1_att= (float*)(ws + 28573696);     // overlay: xWf dead after k41

  k0_cvt  <<<dim3(1250), dim3(256), 0, stream>>>(wq, wk, wihf, wihb,
                                                 bihf, bhhf, bihb, bhhb,
                                                 wqb, wkb, wihfb, wihbb, bgf, bgb);
  k0b_quant<<<dim3(416), dim3(256), 0, stream>>>(whhf, whhb, w8f, w8b, sclf, sclb);
  k3_xw   <<<dim3(256),  dim3(512), 0, stream>>>(x1, seq, wihfb, wihbb, bgf, bgb, xWf, xWb);
  k41_fused<<<dim3(4112), dim3(512), 0, stream>>>(xWf, xWb, w8f, w8b, sclf, sclb, seq, h_ws,
                                                  x2, wqb, bq, wkb, bk, pooled);
  k2_x2p  <<<dim3(1024), dim3(256), 0, stream>>>(pooled, wmha, bmha, x2p);
  k4b_fill<<<dim3(32),   dim3(256), 0, stream>>>(seq, h_ws, wattn, a_ws, amax_ws);
  k5_attn <<<dim3(256),  dim3(256), 0, stream>>>(h_ws, a_ws, amax_ws, x1_att);
  k6_out  <<<dim3(1024), dim3(256), 0, stream>>>(x1_att, x2p, wmlp, bmlp, seq, out);
}

// Round 15
// 1102.355 us; speedup vs baseline: 1.6026x; 1.0007x over previous
//
// NeRTModel_60997125538302 — round 15: fused kernel at 2 blocks/CU.
// r14 fusion worked (1346->1103) but LSTM's 102.9KB LDS forced pooling to 1 blk/CU
// (pooling-bound span 682us). Fix: LSTM gets 6 reg pairs (96 VGPR, ~120 total <= 128)
// + only 4 LDS pool pairs (16KB) -> LSTM LDS 37KB; union = pooling 79.6KB -> 2 blk/CU
// (pooling back to 4 waves/SIMD). LSTM waves get s_setprio(2) to protect the recurrence
// critical path from co-resident pooling waves. Everything else = round 14.

#include <hip/hip_runtime.h>
#include <hip/hip_bf16.h>
#include <cstdint>
#include <cstddef>

typedef unsigned short u16;
typedef __attribute__((ext_vector_type(8))) short short8v;
typedef __attribute__((ext_vector_type(4))) short short4v;
typedef __attribute__((ext_vector_type(4))) float f32x4;
typedef __attribute__((ext_vector_type(4))) int i32x4;

#define MFMA16 __builtin_amdgcn_mfma_f32_16x16x32_bf16
#define MFMAI8 __builtin_amdgcn_mfma_i32_16x16x64_i8

__device__ __forceinline__ float bf2f(u16 u){
  union { unsigned int i; float f; } v; v.i = ((unsigned int)u) << 16; return v.f;
}
__device__ __forceinline__ u16 f2bf(float f){
  union { float f; unsigned int u; } v; v.f = f;
  unsigned int r = v.u + 0x7FFFu + ((v.u >> 16) & 1u);
  return (u16)(r >> 16);
}
__device__ __forceinline__ short8v szero(){
  short8v z;
  #pragma unroll
  for (int i = 0; i < 8; i++) z[i] = 0;
  return z;
}
__device__ __forceinline__ float sigm(float x){ return 1.0f/(1.0f + __expf(-x)); }
__device__ __forceinline__ float tanh_u(float x){
  float e = __expf(2.f*x);              // overflow -> inf -> tanh -> 1 (no NaN)
  return 1.f - 2.f/(e + 1.f);
}
// LDS-visibility-only barrier: does NOT drain vmcnt.
__device__ __forceinline__ void lds_barrier(){
  asm volatile("s_waitcnt lgkmcnt(0)" ::: "memory");
  __builtin_amdgcn_s_barrier();
  __builtin_amdgcn_sched_barrier(0);
}

// ---------------- K0: convert non-recurrent weights f32 -> bf16; fuse LSTM biases ----------------
__global__ void k0_cvt(const float* __restrict__ wq, const float* __restrict__ wk,
                       const float* __restrict__ wihf, const float* __restrict__ wihb,
                       const float* __restrict__ bihf, const float* __restrict__ bhhf,
                       const float* __restrict__ bihb, const float* __restrict__ bhhb,
                       u16* __restrict__ wqb, u16* __restrict__ wkb,
                       u16* __restrict__ wihfb, u16* __restrict__ wihbb,
                       float* __restrict__ bgf, float* __restrict__ bgb){
  int i = blockIdx.x*256 + threadIdx.x;
  if (i < 160000){ wqb[i] = f2bf(wq[i]); wkb[i] = f2bf(wk[i]); }
  if (i < 320000){ wihfb[i] = f2bf(wihf[i]); wihbb[i] = f2bf(wihb[i]); }
  if (i < 800){ bgf[i] = bihf[i] + bhhf[i]; bgb[i] = bihb[i] + bhhb[i]; }
}

// ---------------- K0b: row-quantize W_hh -> i8 [4 gate][208 row][256 k] + scales ----------------
__global__ void k0b_quant(const float* __restrict__ whhf, const float* __restrict__ whhb,
                          signed char* __restrict__ w8f, signed char* __restrict__ w8b,
                          float* __restrict__ sclf, float* __restrict__ sclb){
  const int tid = threadIdx.x, lane = tid & 63, wv = tid >> 6;
  const int widx = blockIdx.x*4 + wv;              // 0..1663
  if (widx < 1600){
    int dir = widx / 800, g = widx - dir*800;
    const float* src = (dir ? whhb : whhf) + (size_t)g*200;
    float mx = 0.f;
    for (int j = lane; j < 200; j += 64) mx = fmaxf(mx, fabsf(src[j]));
    #pragma unroll
    for (int m = 32; m > 0; m >>= 1) mx = fmaxf(mx, __shfl_xor(mx, m, 64));
    float inv = (mx > 0.f) ? 127.f/mx : 0.f;
    int gt = g / 200, hl = g - gt*200;
    signed char* dst = (dir ? w8b : w8f) + (size_t)(gt*208 + hl)*256;
    int e0 = lane*4;
    unsigned int pack = 0u;
    if (e0 < 200){
      #pragma unroll
      for (int r = 0; r < 4; r++){
        int qv = __float2int_rn(src[e0+r]*inv);
        pack |= ((unsigned int)(qv & 255)) << (8*r);
      }
    }
    ((unsigned int*)dst)[lane] = pack;               // lanes 50..63 zero the k-pad
    if (lane == 0) (dir ? sclb : sclf)[g] = mx / 16129.f;   // mx / 127^2
  } else {
    int pr = widx - 1600;                            // 64 pad rows
    int dir = pr >> 5, rem = pr & 31, gt = rem >> 3, hl = 200 + (rem & 7);
    signed char* dst = (dir ? w8b : w8f) + (size_t)(gt*208 + hl)*256;
    ((unsigned int*)dst)[lane] = 0u;
  }
}

// ---------------- K3: xW = x @ W_ih^T + (b_ih+b_hh), layout [t][b32][hu][gt] bf16 ----------------
__launch_bounds__(512)
__global__ void k3_xw(const float* __restrict__ x1, const int* __restrict__ seq,
                      const u16* __restrict__ wihfb, const u16* __restrict__ wihbb,
                      const float* __restrict__ bgf, const float* __restrict__ bgb,
                      u16* __restrict__ xWf, u16* __restrict__ xWb){
  __shared__ u16 xf[12800];
  __shared__ u16 xb[12800];
  const int tid = threadIdx.x;
  const int t = blockIdx.x;
  for (int i = tid; i < 3200; i += 512){
    int b = i / 100, e4 = i - b*100;
    f32x4 vf = *(const f32x4*)&x1[((size_t)b*256 + t)*400 + e4*4];
    int rb = seq[b] - 1 - t; if (rb < 0) rb = 0;     // clip(L-1-t, 0, T-1)
    f32x4 vb = *(const f32x4*)&x1[((size_t)b*256 + rb)*400 + e4*4];
    short4v sf, sb;
    #pragma unroll
    for (int r = 0; r < 4; r++){ sf[r] = f2bf(vf[r]); sb[r] = f2bf(vb[r]); }
    ((short4v*)xf)[i] = sf;
    ((short4v*)xb)[i] = sb;
  }
  __syncthreads();
  const int lane = tid & 63, wv = tid >> 6;
  const int dir = wv >> 2, wl = wv & 3;
  const u16* xs = dir ? xb : xf;
  const u16* W  = dir ? wihbb : wihfb;
  const float* bg = dir ? bgb : bgf;
  u16* xW = dir ? xWb : xWf;
  const int q = lane & 15, kg = lane >> 4;
  short8v A[2][13];
  #pragma unroll
  for (int mt = 0; mt < 2; mt++)
    #pragma unroll
    for (int ksi = 0; ksi < 13; ksi++){
      int e0 = ksi*32 + kg*8;
      A[mt][ksi] = (e0 < 400) ? *(const short8v*)&xs[(mt*16 + q)*400 + e0] : szero();
    }
  for (int nt = wl; nt < 50; nt += 4){
    int g = nt*16 + q;                       // gate row 0..799
    float bv = bg[g];
    f32x4 acc0, acc1;
    acc0[0]=bv; acc0[1]=bv; acc0[2]=bv; acc0[3]=bv; acc1 = acc0;
    const u16* wrow = W + (size_t)g*400;
    #pragma unroll
    for (int ksi = 0; ksi < 13; ksi++){
      int e0 = ksi*32 + kg*8;
      short8v bf = (e0 < 400) ? *(const short8v*)&wrow[e0] : szero();
      acc0 = MFMA16(A[0][ksi], bf, acc0, 0,0,0);
      acc1 = MFMA16(A[1][ksi], bf, acc1, 0,0,0);
    }
    int gt = g / 200, hu = g - gt*200;
    #pragma unroll
    for (int r = 0; r < 4; r++){
      int bl = kg*4 + r;                     // D rows = batch rows
      xW[(((size_t)t*32 +      bl)*200 + hu)*4 + gt] = f2bf(acc0[r]);
      xW[(((size_t)t*32 + 16 + bl)*200 + hu)*4 + gt] = f2bf(acc1[r]);
    }
  }
}

// ---------------- K41: FUSED LSTM (blocks 0-15, 37KB LDS) + pooling (blocks 16+). ----------------
__device__ __forceinline__ void store_gate_f32(int p, const i32x4& acc, int q, int kg,
                                               float* gates, const float* scl_s){
  int gt = p/13, nt = p - gt*13;
  int hu0 = nt*16 + kg*4;
  if (hu0 < 200 && q < 4){
    const f32x4 s4 = *(const f32x4*)&scl_s[gt*200 + hu0];
    #pragma unroll
    for (int r = 0; r < 4; r++)
      gates[q*804 + (hu0+r)*4 + gt] = (float)acc[r]*s4[r];
  }
}

__launch_bounds__(512)
__global__ void k41_fused(const u16* __restrict__ xWf, const u16* __restrict__ xWb,
                          const signed char* __restrict__ w8f, const signed char* __restrict__ w8b,
                          const float* __restrict__ sclf, const float* __restrict__ sclb,
                          const int* __restrict__ seq, float* __restrict__ h_ws,
                          const float* __restrict__ x2,
                          const u16* __restrict__ wqb, const float* __restrict__ bq,
                          const u16* __restrict__ wkb, const float* __restrict__ bk,
                          float* __restrict__ pooled){
  __shared__ __align__(16) char smem[79616];
  const int tid = threadIdx.x;
  const int bid = blockIdx.x;
  const int lane = tid & 63, wv = tid >> 6;
  const int q = lane & 15, kg = lane >> 4;

  if (bid < 16){
    // ============ LSTM path: 6 reg pairs + 4 LDS pool pairs; LDS 37KB ============
    __builtin_amdgcn_s_setprio(2);                     // protect recurrence critical path
    signed char* h8   = (signed char*)smem;            // 4,608
    float* gates      = (float*)(smem + 4608);         // 12,864 -> 17,472
    i32x4* pool       = (i32x4*)(smem + 17472);        // 4*4*64*16 = 16,384 -> 33,856
    float* scl_s      = (float*)(smem + 33856);        // 3,200 -> 37,056
    int* Ls           = (int*)(smem + 37056);          // 16 -> 37,072
    const int dir = bid >> 3, grp = bid & 7;
    const u16* xWd = dir ? xWb : xWf;
    const signed char* w8 = dir ? w8b : w8f;
    const float* scl = dir ? sclb : sclf;
    if (tid < 4) Ls[tid] = seq[grp*4 + tid];
    for (int i = tid; i < 1152; i += 512) ((int*)h8)[i] = 0;
    for (int i = tid; i < 800; i += 512) scl_s[i] = scl[i];
    // pool fill: slot s=0..3 -> pair p=48+s (gt=3, nt=9+s)
    for (int idx = tid; idx < 1024; idx += 512){
      int s = idx >> 8, rem = idx & 255;
      int ksi = rem >> 6, l = rem & 63;
      int qq = l & 15, kk = l >> 4;
      pool[idx] = *(const i32x4*)&w8[(size_t)(3*208 + (9+s)*16 + qq)*256 + ksi*64 + kk*16];
    }
    // register pairs p = wv + 8j, j<6 (96 VGPR)
    i32x4 Wr[6][4];
    #pragma unroll
    for (int j = 0; j < 6; j++){
      int p = wv + 8*j, gt = p/13, nt = p - gt*13;
      #pragma unroll
      for (int ksi = 0; ksi < 4; ksi++)
        Wr[j][ksi] = *(const i32x4*)&w8[(size_t)(gt*208 + nt*16 + q)*256 + ksi*64 + kg*16];
    }
    float cst0 = 0.f, cst1 = 0.f;
    const int c0 = tid,        b0c = c0/200, hu0c = c0 - b0c*200;
    const int qd1 = tid + 512;
    const int b1c = qd1/200,   hu1c = qd1 - b1c*200;
    const int xoff0 = ((grp*4 + b0c)*200 + hu0c)*4;
    const int xoff1 = ((grp*4 + b1c)*200 + hu1c)*4;
    short4v xc0 = *(const short4v*)&xWd[xoff0];
    short4v xc1 = {0,0,0,0};
    if (tid < 288) xc1 = *(const short4v*)&xWd[xoff1];
    __syncthreads();
    #pragma unroll 1
    for (int t = 0; t < 256; t++){
      int tn = (t + 1 < 256) ? t + 1 : 255;
      const u16* xwn = xWd + (size_t)tn*25600;
      short4v xn0 = *(const short4v*)&xwn[xoff0];
      short4v xn1 = {0,0,0,0};
      if (tid < 288) xn1 = *(const short4v*)&xwn[xoff1];
      i32x4 bh[4];
      #pragma unroll
      for (int ksi = 0; ksi < 4; ksi++)
        bh[ksi] = *(const i32x4*)&h8[q*288 + ksi*64 + kg*16];
      #pragma unroll
      for (int j = 0; j < 6; j++){
        i32x4 acc = {0,0,0,0};
        #pragma unroll
        for (int ksi = 0; ksi < 4; ksi++)
          acc = MFMAI8(Wr[j][ksi], bh[ksi], acc, 0,0,0);
        store_gate_f32(wv + 8*j, acc, q, kg, gates, scl_s);
      }
      if (wv < 4){                                   // pool pair p = 48+wv
        i32x4 acc = {0,0,0,0};
        #pragma unroll
        for (int ksi = 0; ksi < 4; ksi++)
          acc = MFMAI8(pool[(wv*4 + ksi)*64 + lane], bh[ksi], acc, 0,0,0);
        store_gate_f32(48 + wv, acc, q, kg, gates, scl_s);
      }
      lds_barrier();
      {
        const f32x4 g4 = *(const f32x4*)&gates[b0c*804 + hu0c*4];
        float gi = g4[0] + bf2f((u16)xc0[0]);
        float gf = g4[1] + bf2f((u16)xc0[1]);
        float gg = g4[2] + bf2f((u16)xc0[2]);
        float go = g4[3] + bf2f((u16)xc0[3]);
        float c = sigm(gf)*cst0 + sigm(gi)*tanh_u(gg);
        cst0 = c;
        float hv = sigm(go)*tanh_u(c);
        h8[b0c*288 + hu0c] = (signed char)__float2int_rn(hv*127.f);
        int gb = grp*4 + b0c;
        if (dir == 0){
          h_ws[((size_t)gb*256 + t)*400 + hu0c] = hv;
        } else {
          int tp = Ls[b0c] - 1 - t;
          if (tp >= 0) h_ws[((size_t)gb*256 + tp)*400 + 200 + hu0c] = hv;
        }
      }
      if (tid < 288){
        const f32x4 g4 = *(const f32x4*)&gates[b1c*804 + hu1c*4];
        float gi = g4[0] + bf2f((u16)xc1[0]);
        float gf = g4[1] + bf2f((u16)xc1[1]);
        float gg = g4[2] + bf2f((u16)xc1[2]);
        float go = g4[3] + bf2f((u16)xc1[3]);
        float c = sigm(gf)*cst1 + sigm(gi)*tanh_u(gg);
        cst1 = c;
        float hv = sigm(go)*tanh_u(c);
        h8[b1c*288 + hu1c] = (signed char)__float2int_rn(hv*127.f);
        int gb = grp*4 + b1c;
        if (dir == 0){
          h_ws[((size_t)gb*256 + t)*400 + hu1c] = hv;
        } else {
          int tp = Ls[b1c] - 1 - t;
          if (tp >= 0) h_ws[((size_t)gb*256 + tp)*400 + 200 + hu1c] = hv;
        }
      }
      lds_barrier();
      xc0 = xn0; xc1 = xn1;
    }
  } else {
    // ============ pooling path (r9 k1 math; 8-way wave split) ============
    u16* tok0  = (u16*)smem;                 // 25,600
    u16* qsb   = (u16*)(smem + 25600);       // 25,856 -> 51,456
    u16* ksb   = (u16*)(smem + 51456);       // 25,856 -> 77,312
    float* msum= (float*)(smem + 77312);     // 2,048 -> 79,360
    float* tval= (float*)(smem + 79360);     // 128
    float* attw= (float*)(smem + 79488);     // 128 -> 79,616
    const int kb = bid - 16;
    const size_t n0 = (size_t)kb * 2;
    const float* src = x2 + n0*6400;
    msum[tid & 511] = 0.f;
    for (int i = tid; i < 3200; i += 512){
      f32x4 v = *(const f32x4*)&src[(size_t)i*4];
      short4v s; s[0]=f2bf(v[0]); s[1]=f2bf(v[1]); s[2]=f2bf(v[2]); s[3]=f2bf(v[3]);
      int j = i / 1600, r = i - j*1600;
      ((short4v*)(tok0 + j*6400))[r] = s;
    }
    __syncthreads();
    {
      const int proj = wv >> 2;              // waves 0-3: q, 4-7: k
      const int jn   = (wv >> 1) & 1;
      const int half = wv & 1;
      const int ntbase = half ? 13 : 0;
      const int ntcnt  = half ? 12 : 13;
      const u16* W    = proj ? wkb : wqb;
      const float* bias = proj ? bk : bq;
      const u16* tokj = tok0 + jn*6400;
      u16* dst = (proj ? ksb : qsb) + jn*6464;
      short8v A[13];
      #pragma unroll
      for (int ksi = 0; ksi < 13; ksi++){
        int e0 = ksi*32 + kg*8;
        A[ksi] = (e0 < 400) ? *(const short8v*)&tokj[q*400 + e0] : szero();
      }
      for (int ti = 0; ti < ntcnt; ti++){
        int col = (ntbase + ti)*16 + q;
        float bv = bias[col];
        f32x4 acc;
        acc[0]=bv; acc[1]=bv; acc[2]=bv; acc[3]=bv;
        const u16* wrow = W + (size_t)col*400;
        #pragma unroll
        for (int ksi = 0; ksi < 13; ksi++){
          int e0 = ksi*32 + kg*8;
          short8v bf = (e0 < 400) ? *(const short8v*)&wrow[e0] : szero();
          acc = MFMA16(A[ksi], bf, acc, 0, 0, 0);
        }
        #pragma unroll
        for (int r = 0; r < 4; r++)          // D: row=(l>>4)*4+r, col=l&15
          dst[(kg*4+r)*404 + col] = f2bf(acc[r]);
      }
    }
    __syncthreads();
    for (int rr = 0; rr < 2; rr++){
      int row = tid + rr*512;
      if (row < 640){
        int j = row / 320, r2 = row - j*320;
        int hh = r2 >> 4, sq = r2 & 15;
        const u16* qrow = qsb + j*6464 + sq*404 + hh*20;
        float qv[20];
        #pragma unroll
        for (int d5 = 0; d5 < 5; d5++){
          short4v v = *(const short4v*)&qrow[d5*4];
          qv[d5*4+0]=bf2f((u16)v[0]); qv[d5*4+1]=bf2f((u16)v[1]);
          qv[d5*4+2]=bf2f((u16)v[2]); qv[d5*4+3]=bf2f((u16)v[3]);
        }
        float sc[16]; float mx = -1e30f;
        const u16* kbase = ksb + j*6464 + hh*20;
        #pragma unroll
        for (int sk = 0; sk < 16; sk++){
          const u16* krow = kbase + sk*404;
          float s = 0.f;
          #pragma unroll
          for (int d5 = 0; d5 < 5; d5++){
            short4v v = *(const short4v*)&krow[d5*4];
            s += qv[d5*4+0]*bf2f((u16)v[0]) + qv[d5*4+1]*bf2f((u16)v[1])
               + qv[d5*4+2]*bf2f((u16)v[2]) + qv[d5*4+3]*bf2f((u16)v[3]);
          }
          s *= 0.22360679775f;               // 1/sqrt(20)
          sc[sk] = s; mx = fmaxf(mx, s);
        }
        float sum = 0.f;
        #pragma unroll
        for (int sk = 0; sk < 16; sk++){ sc[sk] = __expf(sc[sk]-mx); sum += sc[sk]; }
        float inv = 0.05f/sum;               // fold the 1/20 head-mean in
        #pragma unroll
        for (int sk = 0; sk < 16; sk++){
          float v = sc[sk]*inv;
          v += __shfl_xor(v, 16, 64);
          v += __shfl_xor(v, 32, 64);
          if (kg == 0) atomicAdd(&msum[j*256 + sq*16 + sk], v);
        }
      }
    }
    __syncthreads();
    if (tid < 32){
      int j = tid >> 4, sq = tid & 15;
      float s = 0.f;
      #pragma unroll
      for (int sk = 0; sk < 16; sk++) s += msum[j*256 + sq*16+sk];
      tval[j*16 + sq] = s * 0.0625f;
    }
    __syncthreads();
    if (tid < 2){
      float mx = -1e30f;
      for (int i = 0; i < 16; i++) mx = fmaxf(mx, tval[tid*16+i]);
      float sum = 0.f; float ev[16];
      for (int i = 0; i < 16; i++){ ev[i] = __expf(tval[tid*16+i]-mx); sum += ev[i]; }
      float inv = 1.f/sum;
      for (int i = 0; i < 16; i++) attw[tid*16+i] = ev[i]*inv;
    }
    __syncthreads();
    for (int e = tid; e < 800; e += 512){
      int j = e / 400, c = e - j*400;
      float acc = 0.f;
      #pragma unroll
      for (int s = 0; s < 16; s++) acc += attw[j*16+s]*bf2f(tok0[j*6400 + s*400 + c]);
      pooled[(n0+j)*400 + c] = acc;
    }
  }
}

// ---------------- K2: x2p = pooled @ w_mlp_mha^T + b (f32 VALU) ----------------
__global__ void k2_x2p(const float* __restrict__ pooled, const float* __restrict__ wmha,
                       const float* __restrict__ bmha, float* __restrict__ x2p){
  __shared__ float rows[3200];
  const int tid = threadIdx.x;
  const size_t n0 = (size_t)blockIdx.x*8;
  for (int i = tid; i < 3200; i += 256) rows[i] = pooled[n0*400 + i];
  __syncthreads();
  for (int j = tid; j < 400; j += 256){
    float bv = bmha[j];
    float acc[8];
    #pragma unroll
    for (int r = 0; r < 8; r++) acc[r] = bv;
    const float* wr = wmha + (size_t)j*400;
    for (int e = 0; e < 400; e += 4){
      const f32x4 w4 = *(const f32x4*)&wr[e];
      #pragma unroll
      for (int r = 0; r < 8; r++){
        const f32x4 x4 = *(const f32x4*)&rows[r*400 + e];
        acc[r] += x4[0]*w4[0] + x4[1]*w4[1] + x4[2]*w4[2] + x4[3]*w4[3];
      }
    }
    #pragma unroll
    for (int r = 0; r < 8; r++) x2p[(n0+r)*400 + j] = acc[r];
  }
}

// ---------------- K4b: fill bwd rows t>=L AND compute a[b][t] + per-b max ----------------
__global__ void k4b_fill(const int* __restrict__ seq, float* __restrict__ h_ws,
                         const float* __restrict__ wattn,
                         float* __restrict__ a_ws, float* __restrict__ amax_ws){
  __shared__ float a_lds[256];
  const int b = blockIdx.x;
  const int tid = threadIdx.x;
  const int lane = tid & 63, wv = tid >> 6;
  const int L = seq[b];
  const int cnt = (256 - L)*200;
  const float* srcf = h_ws + ((size_t)b*256 + (L-1))*400 + 200;
  for (int i = tid; i < cnt; i += 256){
    int tt = L + i/200, cc = i - (i/200)*200;
    h_ws[((size_t)b*256 + tt)*400 + 200 + cc] = srcf[cc];
  }
  __syncthreads();
  for (int row = wv*64; row < wv*64 + 64; row++){
    float s = 0.f;
    for (int j = lane; j < 400; j += 64)
      s += h_ws[((size_t)b*256 + row)*400 + j] * wattn[j];
    #pragma unroll
    for (int m = 32; m > 0; m >>= 1) s += __shfl_xor(s, m, 64);
    if (lane == 0) a_lds[row] = s;
  }
  __syncthreads();
  a_ws[b*256 + tid] = a_lds[tid];
  if (tid < 64){
    float m = fmaxf(fmaxf(a_lds[tid], a_lds[tid+64]), fmaxf(a_lds[tid+128], a_lds[tid+192]));
    #pragma unroll
    for (int mm = 32; mm > 0; mm >>= 1) m = fmaxf(m, __shfl_xor(m, mm, 64));
    if (tid == 0) amax_ws[b] = m;
  }
}

// ---------------- K5: causal attention as exact cumsum (const per-b max). grid 256. ----------------
__launch_bounds__(256)
__global__ void k5_attn(const float* __restrict__ h_ws, const float* __restrict__ a_ws,
                        const float* __restrict__ amax_ws, float* __restrict__ x1_att){
  __shared__ float tile[256*52];       // [t][col-chunk 50, pad 52], in-place h -> out
  __shared__ float wl[256];
  const int tid = threadIdx.x;
  const int b = blockIdx.x >> 3, ch = blockIdx.x & 7;
  const int c0 = ch*50;
  wl[tid] = __expf(a_ws[b*256 + tid] - amax_ws[b]);
  for (int i = tid; i < 12800; i += 256){
    int r = i / 50, c = i - r*50;
    tile[r*52 + c] = h_ws[((size_t)b*256 + r)*400 + c0 + c];
  }
  __syncthreads();
  if (tid < 50){
    float den = 0.f, num = 0.f;
    #pragma unroll 4
    for (int t = 0; t < 256; t++){
      float w = wl[t];
      den += w;
      num += w * tile[t*52 + tid];
      tile[t*52 + tid] = num/den;
    }
  }
  __syncthreads();
  for (int i = tid; i < 12800; i += 256){
    int r = i / 50, c = i - r*50;
    x1_att[((size_t)b*256 + r)*400 + c0 + c] = tile[r*52 + c];
  }
}

// ---------------- K6: out = [x1_att ; x2p] @ w_mlp^T + b, masked, f32 ----------------
__global__ void k6_out(const float* __restrict__ x1_att, const float* __restrict__ x2p,
                       const float* __restrict__ wmlp, const float* __restrict__ bmlp,
                       const int* __restrict__ seq, float* __restrict__ out){
  __shared__ float rows[8*800];
  const int tid = threadIdx.x;
  const size_t n0 = (size_t)blockIdx.x*8;
  const int b = (int)(n0 >> 8), t0 = (int)(n0 & 255);
  const int L = seq[b];
  for (int i = tid; i < 3200; i += 256){
    int r = i / 400, e = i - r*400;
    rows[r*800 + e]       = x1_att[(n0 + r)*400 + e];
    rows[r*800 + 400 + e] = x2p  [(n0 + r)*400 + e];
  }
  __syncthreads();
  for (int e = tid; e < 400; e += 256){
    float bv = bmlp[e];
    float acc[8];
    #pragma unroll
    for (int r = 0; r < 8; r++) acc[r] = bv;
    const float* wr = wmlp + (size_t)e*800;
    for (int j = 0; j < 800; j += 4){
      const f32x4 w4 = *(const f32x4*)&wr[j];
      #pragma unroll
      for (int r = 0; r < 8; r++){
        const f32x4 x4 = *(const f32x4*)&rows[r*800 + j];
        acc[r] += x4[0]*w4[0] + x4[1]*w4[1] + x4[2]*w4[2] + x4[3]*w4[3];
      }
    }
    #pragma unroll
    for (int r = 0; r < 8; r++){
      float v = (t0 + r < L) ? acc[r] : 0.f;
      out[(n0 + r)*400 + e] = v;
    }
  }
}

extern "C" void kernel_launch(void* const* d_in, const int* in_sizes, int n_in,
                              void* d_out, int out_size, void* d_ws, size_t ws_size,
                              hipStream_t stream){
  const float* x1   = (const float*)d_in[0];
  const float* x2   = (const float*)d_in[1];
  // d_in[2] = cate: unused by the reference
  const int*   seq  = (const int*)d_in[3];
  const float* wihf = (const float*)d_in[4];
  const float* whhf = (const float*)d_in[5];
  const float* bihf = (const float*)d_in[6];
  const float* bhhf = (const float*)d_in[7];
  const float* wihb = (const float*)d_in[8];
  const float* whhb = (const float*)d_in[9];
  const float* bihb = (const float*)d_in[10];
  const float* bhhb = (const float*)d_in[11];
  const float* wq   = (const float*)d_in[12];
  const float* bq   = (const float*)d_in[13];
  const float* wk   = (const float*)d_in[14];
  const float* bk   = (const float*)d_in[15];
  const float* wmha = (const float*)d_in[16];
  const float* bmha = (const float*)d_in[17];
  const float* wattn= (const float*)d_in[18];
  // d_in[19] = b_attn: cancels in softmax
  const float* wmlp = (const float*)d_in[20];
  const float* bmlp = (const float*)d_in[21];
  float* out = (float*)d_out;

  char* ws = (char*)d_ws;
  u16*  wqb    = (u16*)(ws + 0);              // 320,000 B
  u16*  wkb    = (u16*)(ws + 320000);         // 320,000
  u16*  wihfb  = (u16*)(ws + 640000);         // 640,000
  u16*  wihbb  = (u16*)(ws + 1280000);        // 640,000
  signed char* w8f  = (signed char*)(ws + 1920000);  // 212,992
  signed char* w8b  = (signed char*)(ws + 2132992);  // 212,992
  float* sclf  = (float*)(ws + 2345984);      // 3,200
  float* sclb  = (float*)(ws + 2349184);      // 3,200
  float* bgf   = (float*)(ws + 2352384);      // 3,200
  float* bgb   = (float*)(ws + 2355584);      // 3,200 -> end 2,358,784
  float* pooled= (float*)(ws + 2359296);      // 13,107,200
  float* x2p   = (float*)(ws + 15466496);     // 13,107,200
  u16*  xWf    = (u16*)(ws + 28573696);       // 13,107,200
  u16*  xWb    = (u16*)(ws + 41680896);       // 13,107,200
  float* h_ws  = (float*)(ws + 54788096);     // 13,107,200 -> end 67,895,296
  float* a_ws  = (float*)(ws + 67895296);     // 32,768
  float* amax_ws=(float*)(ws + 67928064);     // 128 (end ~67.93MB)
  float* x1_att= (float*)(ws + 28573696);     // overlay: xWf dead after k41

  k0_cvt  <<<dim3(1250), dim3(256), 0, stream>>>(wq, wk, wihf, wihb,
                                                 bihf, bhhf, bihb, bhhb,
                                                 wqb, wkb, wihfb, wihbb, bgf, bgb);
  k0b_quant<<<dim3(416), dim3(256), 0, stream>>>(whhf, whhb, w8f, w8b, sclf, sclb);
  k3_xw   <<<dim3(256),  dim3(512), 0, stream>>>(x1, seq, wihfb, wihbb, bgf, bgb, xWf, xWb);
  k41_fused<<<dim3(4112), dim3(512), 0, stream>>>(xWf, xWb, w8f, w8b, sclf, sclb, seq, h_ws,
                                                  x2, wqb, bq, wkb, bk, pooled);
  k2_x2p  <<<dim3(1024), dim3(256), 0, stream>>>(pooled, wmha, bmha, x2p);
  k4b_fill<<<dim3(32),   dim3(256), 0, stream>>>(seq, h_ws, wattn, a_ws, amax_ws);
  k5_attn <<<dim3(256),  dim3(256), 0, stream>>>(h_ws, a_ws, amax_ws, x1_att);
  k6_out  <<<dim3(1024), dim3(256), 0, stream>>>(x1_att, x2p, wmlp, bmlp, seq, out);
}